// Round 2
// baseline (1277.833 us; speedup 1.0000x reference)
//
#include <hip/hip_runtime.h>
#include <hip/hip_bf16.h>

#define BB 8
#define CDIM 256
#define PP 4096
#define NHEADS 8
#define DHEAD 64
#define INNER 512
#define NBH 64

using bf16 = __hip_bfloat16;

__device__ __forceinline__ float b2f(bf16 x) { return __bfloat162float(x); }
__device__ __forceinline__ bf16 f2b(float x) { return __float2bfloat16(x); }

// ---------------- K1: channel layernorm of an input tensor -> fp32 ----------------
__global__ __launch_bounds__(256) void ln_in_kernel(const float* __restrict__ x,
                                                    const float* __restrict__ g,
                                                    const float* __restrict__ bb,
                                                    float* __restrict__ out) {
    int b = blockIdx.y;
    int p = blockIdx.x * 256 + threadIdx.x;
    const float* xb = x + (size_t)b * CDIM * PP + p;
    float s = 0.f, sq = 0.f;
    for (int c = 0; c < CDIM; ++c) {
        float v = xb[(size_t)c * PP];
        s += v; sq += v * v;
    }
    float mean = s * (1.f / CDIM);
    float var  = sq * (1.f / CDIM) - mean * mean;
    float rstd = rsqrtf(var + 1e-5f);
    float* ob = out + (size_t)b * CDIM * PP + p;
    for (int c = 0; c < CDIM; ++c) {
        float v = xb[(size_t)c * PP];
        ob[(size_t)c * PP] = (v - mean) * rstd * g[c] + bb[c];
    }
}

// ---------------- K2: conv1x1 GEMM (fp32 in, bf16 out) + l2norm + fp32 score reductions ----
// out[b,o,p] = sum_c W[o,c] * X[b,c,p].  o < norm_below: l2norm over the head's 64
// channels (one tile == one head) -> dstA; else raw -> dstB.
// mode 0 (kv): normed tiles are K -> emit k_rowsum (direct) + k_colsum (atomic), fp32.
// mode 1 (q):  all tiles normed -> emit q_probe (atomic), fp32.
__global__ __launch_bounds__(256) void gemm_qkv_kernel(const float* __restrict__ Wm,
                                                       const float* __restrict__ X,
                                                       bf16* __restrict__ dstA,
                                                       bf16* __restrict__ dstB,
                                                       int Kdim, int norm_below, int mode,
                                                       float* __restrict__ k_rowsum,
                                                       float* __restrict__ k_colsum,
                                                       float* __restrict__ q_probe) {
    __shared__ float Wt[64][65];   // [k][o]
    __shared__ float Xt[64][65];   // [k][p]
    __shared__ float red[16][64];
    __shared__ float rinv[64];

    int b  = blockIdx.z;
    int o0 = blockIdx.y * 64;
    int p0 = blockIdx.x * 64;
    int tid = threadIdx.x;
    int tx = tid & 15, ty = tid >> 4;

    float acc[4][4] = {};

    for (int k0 = 0; k0 < Kdim; k0 += 64) {
#pragma unroll
        for (int i = 0; i < 16; ++i) {
            int idx = tid + i * 256;
            int r = idx >> 6, cc = idx & 63;
            Wt[cc][r] = Wm[(size_t)(o0 + r) * Kdim + (k0 + cc)];
            Xt[r][cc] = X[((size_t)b * Kdim + (k0 + r)) * PP + (p0 + cc)];
        }
        __syncthreads();
#pragma unroll 8
        for (int kk = 0; kk < 64; ++kk) {
            float a[4], bv[4];
#pragma unroll
            for (int i = 0; i < 4; ++i) a[i] = Wt[kk][ty * 4 + i];
#pragma unroll
            for (int j = 0; j < 4; ++j) bv[j] = Xt[kk][tx * 4 + j];
#pragma unroll
            for (int i = 0; i < 4; ++i)
#pragma unroll
                for (int j = 0; j < 4; ++j)
                    acc[i][j] = fmaf(a[i], bv[j], acc[i][j]);
        }
        __syncthreads();
    }

    bool donorm = (o0 < norm_below);
    if (donorm) {
#pragma unroll
        for (int j = 0; j < 4; ++j) {
            float sj = 0.f;
#pragma unroll
            for (int i = 0; i < 4; ++i) sj += acc[i][j] * acc[i][j];
            red[ty][tx * 4 + j] = sj;
        }
        __syncthreads();
        if (tid < 64) {
            float s = 0.f;
#pragma unroll
            for (int yy = 0; yy < 16; ++yy) s += red[yy][tid];
            rinv[tid] = 1.f / fmaxf(sqrtf(s), 1e-12f);
        }
        __syncthreads();
#pragma unroll
        for (int i = 0; i < 4; ++i)
#pragma unroll
            for (int j = 0; j < 4; ++j)
                acc[i][j] *= rinv[tx * 4 + j];   // normalized fp32 values
    }

    int oo = donorm ? o0 : (o0 - norm_below);
    bf16* dest = donorm ? dstA : dstB;
#pragma unroll
    for (int i = 0; i < 4; ++i) {
        int oc = oo + ty * 4 + i;             // channel within 512
        int bh = b * NHEADS + (oc >> 6);
        int d  = oc & 63;
        bf16* drow = dest + ((size_t)bh * DHEAD + d) * PP + p0;
#pragma unroll
        for (int j = 0; j < 4; ++j) drow[tx * 4 + j] = f2b(acc[i][j]);
    }

    if (donorm) {
        int bh = b * NHEADS + (o0 >> 6);
        int h  = p0 >> 6;                      // one tile == one spatial row
        float part[4];
#pragma unroll
        for (int i = 0; i < 4; ++i) {
            float s = 0.f;
#pragma unroll
            for (int j = 0; j < 4; ++j)
                s += (mode == 0) ? fabsf(acc[i][j]) : acc[i][j];
            part[i] = s;
        }
        __syncthreads();                       // red reuse guard
#pragma unroll
        for (int i = 0; i < 4; ++i) red[tx][ty * 4 + i] = part[i];
        __syncthreads();
        if (tid < 64) {
            float s = 0.f;
#pragma unroll
            for (int t = 0; t < 16; ++t) s += red[t][tid];
            if (mode == 0) k_rowsum[((size_t)bh * 64 + h) * 64 + tid] = s;
            else           atomicAdd(&q_probe[(size_t)bh * 64 + tid], s);
        }
        if (mode == 0) {
#pragma unroll
            for (int i = 0; i < 4; ++i)
#pragma unroll
                for (int j = 0; j < 4; ++j)
                    atomicAdd(&k_colsum[((size_t)bh * 64 + (ty * 4 + i)) * 64 + (tx * 4 + j)],
                              fabsf(acc[i][j]));
        }
    }
}

// ---------------- K4: scores, top-8 rows/cols, gather k_sel/v_sel ----------------
__global__ __launch_bounds__(256) void select_gather_kernel(const float* __restrict__ q_probe,
                                                            const float* __restrict__ k_rowsum,
                                                            const float* __restrict__ k_colsum,
                                                            const bf16* __restrict__ kn,
                                                            const bf16* __restrict__ vs,
                                                            bf16* __restrict__ k_sel,
                                                            bf16* __restrict__ v_sel) {
    int bh = blockIdx.x;
    int tid = threadIdx.x;
    __shared__ float qp[64];
    __shared__ int selh[8], selw[8];
    if (tid < 64) qp[tid] = q_probe[(size_t)bh * 64 + tid];
    __syncthreads();
    if (tid < 128) {
        int isCol = tid >> 6;
        int x = tid & 63;      // lane id within this wave
        float sv = 0.f;
        if (isCol) {
            for (int d = 0; d < 64; ++d) sv += qp[d] * k_colsum[((size_t)bh * 64 + d) * 64 + x];
        } else {
            for (int d = 0; d < 64; ++d) sv += qp[d] * k_rowsum[((size_t)bh * 64 + x) * 64 + d];
        }
        float v = sv;
        for (int it = 0; it < 8; ++it) {
            float bv = v; int bi = x;
#pragma unroll
            for (int off = 32; off; off >>= 1) {
                float ov = __shfl_xor(bv, off);
                int   oi = __shfl_xor(bi, off);
                if (ov > bv || (ov == bv && oi < bi)) { bv = ov; bi = oi; }
            }
            if (x == 0) { if (isCol) selw[it] = bi; else selh[it] = bi; }
            if (x == bi) v = -3.4e38f;
        }
    }
    __syncthreads();
    for (int idx = tid; idx < 4096; idx += 256) {
        int j = idx >> 6, d = idx & 63;     // j = r*8+s
        int p = selh[j >> 3] * 64 + selw[j & 7];
        k_sel[(size_t)bh * 4096 + idx] = kn[((size_t)bh * 64 + d) * PP + p];
        v_sel[(size_t)bh * 4096 + idx] = vs[((size_t)bh * 64 + d) * PP + p];
    }
}

// ---------------- K5: attention over the 64 selected kv positions ----------------
__global__ __launch_bounds__(256) void attn_kernel(const bf16* __restrict__ qn,
                                                   const bf16* __restrict__ k_sel,
                                                   const bf16* __restrict__ v_sel,
                                                   bf16* __restrict__ attn_out) {
    int bh = blockIdx.y;
    int p = blockIdx.x * 256 + threadIdx.x;
    __shared__ float ks[64][65];
    __shared__ float vls[64][65];
    for (int idx = threadIdx.x; idx < 4096; idx += 256) {
        int j = idx >> 6, d = idx & 63;
        ks[j][d]  = b2f(k_sel[(size_t)bh * 4096 + idx]);
        vls[j][d] = b2f(v_sel[(size_t)bh * 4096 + idx]);
    }
    __syncthreads();
    float sim[64];
#pragma unroll
    for (int j = 0; j < 64; ++j) sim[j] = 0.f;
    const bf16* qb = qn + (size_t)bh * 64 * PP + p;
    for (int d = 0; d < 64; ++d) {
        float qd = b2f(qb[(size_t)d * PP]);
#pragma unroll
        for (int j = 0; j < 64; ++j) sim[j] = fmaf(qd, ks[j][d], sim[j]);
    }
    float m = -3.4e38f;
#pragma unroll
    for (int j = 0; j < 64; ++j) m = fmaxf(m, sim[j]);
    float l = 0.f;
#pragma unroll
    for (int j = 0; j < 64; ++j) { sim[j] = __expf(sim[j] - m); l += sim[j]; }
    float rl = 1.f / l;
    bf16* ob = attn_out + (size_t)bh * 64 * PP + p;
    for (int d = 0; d < 64; ++d) {
        float acc = 0.f;
#pragma unroll
        for (int j = 0; j < 64; ++j) acc = fmaf(sim[j], vls[j][d], acc);
        ob[(size_t)d * PP] = f2b(acc * rl);
    }
}

// ---------------- K6: w_out GEMM (bf16 X) -> y fp32 ----------------
__global__ __launch_bounds__(256) void gemm_out_kernel(const float* __restrict__ Wm,
                                                       const bf16* __restrict__ X,
                                                       float* __restrict__ Y) {
    __shared__ float Wt[64][65];   // [k][o]
    __shared__ float Xt[64][65];   // [k][p]
    int b  = blockIdx.z;
    int o0 = blockIdx.y * 64;
    int p0 = blockIdx.x * 64;
    int tid = threadIdx.x;
    int tx = tid & 15, ty = tid >> 4;
    float acc[4][4] = {};
    for (int k0 = 0; k0 < INNER; k0 += 64) {
#pragma unroll
        for (int i = 0; i < 16; ++i) {
            int idx = tid + i * 256;
            int r = idx >> 6, cc = idx & 63;
            Wt[cc][r] = Wm[(size_t)(o0 + r) * INNER + (k0 + cc)];
            Xt[r][cc] = b2f(X[((size_t)b * INNER + (k0 + r)) * PP + (p0 + cc)]);
        }
        __syncthreads();
#pragma unroll 8
        for (int kk = 0; kk < 64; ++kk) {
            float a[4], bv[4];
#pragma unroll
            for (int i = 0; i < 4; ++i) a[i] = Wt[kk][ty * 4 + i];
#pragma unroll
            for (int j = 0; j < 4; ++j) bv[j] = Xt[kk][tx * 4 + j];
#pragma unroll
            for (int i = 0; i < 4; ++i)
#pragma unroll
                for (int j = 0; j < 4; ++j)
                    acc[i][j] = fmaf(a[i], bv[j], acc[i][j]);
        }
        __syncthreads();
    }
#pragma unroll
    for (int i = 0; i < 4; ++i) {
        float* yrow = Y + ((size_t)b * CDIM + (o0 + ty * 4 + i)) * PP + p0;
#pragma unroll
        for (int j = 0; j < 4; ++j) yrow[tx * 4 + j] = acc[i][j];
    }
}

// ---------------- K7: final LN + gamma*out + residual ----------------
__global__ __launch_bounds__(256) void final_ln_kernel(const float* __restrict__ y,
                                                       const float* __restrict__ g,
                                                       const float* __restrict__ bb,
                                                       const float* __restrict__ gamma,
                                                       const float* __restrict__ resid,
                                                       float* __restrict__ out) {
    int b = blockIdx.y;
    int p = blockIdx.x * 256 + threadIdx.x;
    const float* yb = y + (size_t)b * CDIM * PP + p;
    float s = 0.f, sq = 0.f;
    for (int c = 0; c < CDIM; ++c) {
        float v = yb[(size_t)c * PP];
        s += v; sq += v * v;
    }
    float mean = s * (1.f / CDIM);
    float var  = sq * (1.f / CDIM) - mean * mean;
    float rstd = rsqrtf(var + 1e-5f);
    float gm = gamma[0];
    const float* rb = resid + (size_t)b * CDIM * PP + p;
    float* ob = out + (size_t)b * CDIM * PP + p;
    for (int c = 0; c < CDIM; ++c) {
        float v = yb[(size_t)c * PP];
        float xn = (v - mean) * rstd * g[c] + bb[c];
        ob[(size_t)c * PP] = gm * xn + rb[(size_t)c * PP];
    }
}

extern "C" void kernel_launch(void* const* d_in, const int* in_sizes, int n_in,
                              void* d_out, int out_size, void* d_ws, size_t ws_size,
                              hipStream_t stream) {
    const float* query_source = (const float*)d_in[0];
    const float* context      = (const float*)d_in[1];
    const float* cn_g = (const float*)d_in[2];
    const float* cn_b = (const float*)d_in[3];
    const float* qn_g = (const float*)d_in[4];
    const float* qn_b = (const float*)d_in[5];
    const float* on_g = (const float*)d_in[6];
    const float* on_b = (const float*)d_in[7];
    const float* w_kv = (const float*)d_in[8];
    const float* w_q  = (const float*)d_in[9];
    const float* w_out= (const float*)d_in[10];
    const float* gamma= (const float*)d_in[11];
    float* out = (float*)d_out;

    char* ws = (char*)d_ws;
    // Region A [0,32M): fp32 staging (ctx_n -> qs_n) then bf16 attn_out (time-shared)
    float* A      = (float*)(ws + 0);           // 33,554,432 B
    bf16*  attn_o = (bf16*)(ws + 0);            // 33,554,432 B (A dead by then)
    // Region B [32M,64M): bf16 k_n, later fp32 y (k dead after gather)
    bf16*  k_n   = (bf16*)(ws + 33554432);
    float* y     = (float*)(ws + 33554432);
    bf16*  v_s   = (bf16*)(ws + 67108864);      // 32M
    bf16*  q_n   = (bf16*)(ws + 100663296);     // 32M
    float* q_probe  = (float*)(ws + 134217728); // 16,384 B   (zeroed)
    float* k_colsum = (float*)(ws + 134234112); // 1,048,576 B (zeroed, contiguous w/ q_probe)
    float* k_rowsum = (float*)(ws + 135282688); // 1,048,576 B
    bf16*  k_sel = (bf16*)(ws + 136331264);     // 524,288 B
    bf16*  v_sel = (bf16*)(ws + 136855552);     // 524,288 B  (end: 137,379,840)

    hipMemsetAsync(ws + 134217728, 0, 16384 + 1048576, stream);

    dim3 blk(256);
    // ctx LN -> A ; kv GEMM consumes A
    ln_in_kernel<<<dim3(16, BB), blk, 0, stream>>>(context, cn_g, cn_b, A);
    gemm_qkv_kernel<<<dim3(64, 16, BB), blk, 0, stream>>>(w_kv, A, k_n, v_s, CDIM, 512, 0,
                                                          k_rowsum, k_colsum, q_probe);
    // qs LN -> A (reuse) ; q GEMM consumes A
    ln_in_kernel<<<dim3(16, BB), blk, 0, stream>>>(query_source, qn_g, qn_b, A);
    gemm_qkv_kernel<<<dim3(64, 8, BB), blk, 0, stream>>>(w_q, A, q_n, nullptr, CDIM, 512, 1,
                                                         k_rowsum, k_colsum, q_probe);
    select_gather_kernel<<<dim3(64), blk, 0, stream>>>(q_probe, k_rowsum, k_colsum,
                                                       k_n, v_s, k_sel, v_sel);
    attn_kernel<<<dim3(16, NBH), blk, 0, stream>>>(q_n, k_sel, v_sel, attn_o);
    gemm_out_kernel<<<dim3(64, 4, BB), blk, 0, stream>>>(w_out, attn_o, y);
    final_ln_kernel<<<dim3(16, BB), blk, 0, stream>>>(y, on_g, on_b, gamma, query_source, out);
}

// Round 3
// 716.939 us; speedup vs baseline: 1.7823x; 1.7823x over previous
//
#include <hip/hip_runtime.h>
#include <hip/hip_bf16.h>

#define BB 8
#define CDIM 256
#define PP 4096
#define NHEADS 8
#define DHEAD 64
#define INNER 512
#define NBH 64

using bf16 = __hip_bfloat16;
typedef short short8 __attribute__((ext_vector_type(8)));
typedef float f32x4 __attribute__((ext_vector_type(4)));

__device__ __forceinline__ float b2f(bf16 x) { return __bfloat162float(x); }
__device__ __forceinline__ bf16 f2b(float x) { return __float2bfloat16(x); }

// bf16 round-to-nearest-even via bit ops (keeps everything in integer regs)
__device__ __forceinline__ unsigned short f2h(float x) {
    union { float f; unsigned u; } c; c.f = x;
    unsigned r = c.u + 0x7FFF + ((c.u >> 16) & 1);
    return (unsigned short)(r >> 16);
}
__device__ __forceinline__ float h2f(unsigned short h) {
    union { float f; unsigned u; } c; c.u = ((unsigned)h) << 16;
    return c.f;
}

// XOR-swizzled byte offset inside a [64 rows][128 B] LDS tile (G4 fix)
__device__ __forceinline__ int sw(int row, int kb) {
    return row * 128 + (kb ^ ((row & 7) << 4));
}

// ---------------- K1: channel layernorm -> fp32 ----------------
__global__ __launch_bounds__(256) void ln_in_kernel(const float* __restrict__ x,
                                                    const float* __restrict__ g,
                                                    const float* __restrict__ bb,
                                                    float* __restrict__ out) {
    int b = blockIdx.y;
    int p = blockIdx.x * 256 + threadIdx.x;
    const float* xb = x + (size_t)b * CDIM * PP + p;
    float s = 0.f, sq = 0.f;
    for (int c = 0; c < CDIM; ++c) {
        float v = xb[(size_t)c * PP];
        s += v; sq += v * v;
    }
    float mean = s * (1.f / CDIM);
    float var  = sq * (1.f / CDIM) - mean * mean;
    float rstd = rsqrtf(var + 1e-5f);
    float* ob = out + (size_t)b * CDIM * PP + p;
    for (int c = 0; c < CDIM; ++c) {
        float v = xb[(size_t)c * PP];
        ob[(size_t)c * PP] = (v - mean) * rstd * g[c] + bb[c];
    }
}

// ---------------- K2: MFMA conv1x1 GEMM, bf16x3 (fp32-accurate) ----------------
// out[b,o,p] = sum_c W[o,c]*X[b,c,p].  Same epilogue contract as the verified
// Round-2 kernel: l2norm + bf16 folded store + fp32 score reductions.
__global__ __launch_bounds__(256) void mfma_qkv_kernel(const float* __restrict__ Wm,
                                                       const float* __restrict__ X,
                                                       bf16* __restrict__ dstA,
                                                       bf16* __restrict__ dstB,
                                                       int Kdim, int norm_below, int mode,
                                                       float* __restrict__ k_rowsum,
                                                       float* __restrict__ k_colsum,
                                                       float* __restrict__ q_probe) {
    __shared__ alignas(16) char smraw[32768];   // WH|WL|XH|XL, later C[64][65] fp32
    __shared__ float red[16][64];
    __shared__ float rinv[64];
    char* WH = smraw;
    char* WL = smraw + 8192;
    char* XH = smraw + 16384;
    char* XL = smraw + 24576;
    float* C = (float*)smraw;

    int b  = blockIdx.z;
    int o0 = blockIdx.x * 64;
    int p0 = blockIdx.y * 64;
    int tid = threadIdx.x;

    // staging roles
    int o_s = tid >> 2, segW = tid & 3;     // W: row o_s, 16 k each
    int p_l = tid & 63, kseg = tid >> 6;    // X: row p_l (transposed), 16 k each
    // mfma roles
    int l = tid & 63, w = tid >> 6;
    int wm = w >> 1, wn = w & 1;
    int lr = l & 15, lk = l >> 4;

    f32x4 acc[2][2] = {};

    for (int k0 = 0; k0 < Kdim; k0 += 64) {
        // ---- stage W (rows=o, cols=k), split hi/lo ----
        {
            const float* wg = Wm + (size_t)(o0 + o_s) * Kdim + (k0 + segW * 16);
            short8 h0, h1, lo0, lo1;
#pragma unroll
            for (int i = 0; i < 16; ++i) {
                float v = wg[i];
                unsigned short hb = f2h(v);
                unsigned short lb = f2h(v - h2f(hb));
                if (i < 8) { h0[i] = (short)hb; lo0[i] = (short)lb; }
                else       { h1[i - 8] = (short)hb; lo1[i - 8] = (short)lb; }
            }
            *(short8*)(WH + sw(o_s, segW * 32))      = h0;
            *(short8*)(WH + sw(o_s, segW * 32 + 16)) = h1;
            *(short8*)(WL + sw(o_s, segW * 32))      = lo0;
            *(short8*)(WL + sw(o_s, segW * 32 + 16)) = lo1;
        }
        // ---- stage X transposed (rows=p, cols=k), split hi/lo ----
        {
            const float* xg = X + ((size_t)b * Kdim + (k0 + kseg * 16)) * PP + p0 + p_l;
            short8 h0, h1, lo0, lo1;
#pragma unroll
            for (int i = 0; i < 16; ++i) {
                float v = xg[(size_t)i * PP];
                unsigned short hb = f2h(v);
                unsigned short lb = f2h(v - h2f(hb));
                if (i < 8) { h0[i] = (short)hb; lo0[i] = (short)lb; }
                else       { h1[i - 8] = (short)hb; lo1[i - 8] = (short)lb; }
            }
            *(short8*)(XH + sw(p_l, kseg * 32))      = h0;
            *(short8*)(XH + sw(p_l, kseg * 32 + 16)) = h1;
            *(short8*)(XL + sw(p_l, kseg * 32))      = lo0;
            *(short8*)(XL + sw(p_l, kseg * 32 + 16)) = lo1;
        }
        __syncthreads();
#pragma unroll
        for (int kk = 0; kk < 2; ++kk) {
            int kb = kk * 64 + lk * 16;
            short8 ah[2], al[2], bh[2], bl[2];
#pragma unroll
            for (int f = 0; f < 2; ++f) {
                ah[f] = *(short8*)(WH + sw(wm * 32 + f * 16 + lr, kb));
                al[f] = *(short8*)(WL + sw(wm * 32 + f * 16 + lr, kb));
                bh[f] = *(short8*)(XH + sw(wn * 32 + f * 16 + lr, kb));
                bl[f] = *(short8*)(XL + sw(wn * 32 + f * 16 + lr, kb));
            }
#pragma unroll
            for (int fm = 0; fm < 2; ++fm)
#pragma unroll
                for (int fn = 0; fn < 2; ++fn) {
                    acc[fm][fn] = __builtin_amdgcn_mfma_f32_16x16x32_bf16(ah[fm], bh[fn], acc[fm][fn], 0, 0, 0);
                    acc[fm][fn] = __builtin_amdgcn_mfma_f32_16x16x32_bf16(ah[fm], bl[fn], acc[fm][fn], 0, 0, 0);
                    acc[fm][fn] = __builtin_amdgcn_mfma_f32_16x16x32_bf16(al[fm], bh[fn], acc[fm][fn], 0, 0, 0);
                }
        }
        __syncthreads();
    }

    // ---- dump fp32 C tile to LDS (C layout: col=lane&15, row=(lane>>4)*4+reg) ----
#pragma unroll
    for (int fm = 0; fm < 2; ++fm)
#pragma unroll
        for (int fn = 0; fn < 2; ++fn)
#pragma unroll
            for (int r = 0; r < 4; ++r)
                C[(wm * 32 + fm * 16 + lk * 4 + r) * 65 + wn * 32 + fn * 16 + lr] = acc[fm][fn][r];
    __syncthreads();

    // ---- re-read in Round-2 thread layout: a2[i][j] = out[o0+ty*4+i][p0+tx*4+j] ----
    int tx = tid & 15, ty = tid >> 4;
    float a2[4][4];
#pragma unroll
    for (int i = 0; i < 4; ++i)
#pragma unroll
        for (int j = 0; j < 4; ++j)
            a2[i][j] = C[(ty * 4 + i) * 65 + tx * 4 + j];

    // ---- verified Round-2 epilogue ----
    bool donorm = (o0 < norm_below);
    if (donorm) {
#pragma unroll
        for (int j = 0; j < 4; ++j) {
            float sj = 0.f;
#pragma unroll
            for (int i = 0; i < 4; ++i) sj += a2[i][j] * a2[i][j];
            red[ty][tx * 4 + j] = sj;
        }
        __syncthreads();
        if (tid < 64) {
            float s = 0.f;
#pragma unroll
            for (int yy = 0; yy < 16; ++yy) s += red[yy][tid];
            rinv[tid] = 1.f / fmaxf(sqrtf(s), 1e-12f);
        }
        __syncthreads();
#pragma unroll
        for (int i = 0; i < 4; ++i)
#pragma unroll
            for (int j = 0; j < 4; ++j)
                a2[i][j] *= rinv[tx * 4 + j];
    }

    int oo = donorm ? o0 : (o0 - norm_below);
    bf16* dest = donorm ? dstA : dstB;
#pragma unroll
    for (int i = 0; i < 4; ++i) {
        int oc = oo + ty * 4 + i;
        int bh = b * NHEADS + (oc >> 6);
        int d  = oc & 63;
        bf16* drow = dest + ((size_t)bh * DHEAD + d) * PP + p0;
#pragma unroll
        for (int j = 0; j < 4; ++j) drow[tx * 4 + j] = f2b(a2[i][j]);
    }

    if (donorm) {
        int bh = b * NHEADS + (o0 >> 6);
        int h  = p0 >> 6;
        float part[4];
#pragma unroll
        for (int i = 0; i < 4; ++i) {
            float s = 0.f;
#pragma unroll
            for (int j = 0; j < 4; ++j)
                s += (mode == 0) ? fabsf(a2[i][j]) : a2[i][j];
            part[i] = s;
        }
        __syncthreads();   // red reuse guard
#pragma unroll
        for (int i = 0; i < 4; ++i) red[tx][ty * 4 + i] = part[i];
        __syncthreads();
        if (tid < 64) {
            float s = 0.f;
#pragma unroll
            for (int t = 0; t < 16; ++t) s += red[t][tid];
            if (mode == 0) k_rowsum[((size_t)bh * 64 + h) * 64 + tid] = s;
            else           atomicAdd(&q_probe[(size_t)bh * 64 + tid], s);
        }
        if (mode == 0) {
#pragma unroll
            for (int i = 0; i < 4; ++i)
#pragma unroll
                for (int j = 0; j < 4; ++j)
                    atomicAdd(&k_colsum[((size_t)bh * 64 + (ty * 4 + i)) * 64 + (tx * 4 + j)],
                              fabsf(a2[i][j]));
        }
    }
}

// ---------------- K4: scores, top-8 rows/cols, gather ----------------
__global__ __launch_bounds__(256) void select_gather_kernel(const float* __restrict__ q_probe,
                                                            const float* __restrict__ k_rowsum,
                                                            const float* __restrict__ k_colsum,
                                                            const bf16* __restrict__ kn,
                                                            const bf16* __restrict__ vs,
                                                            bf16* __restrict__ k_sel,
                                                            bf16* __restrict__ v_sel) {
    int bh = blockIdx.x;
    int tid = threadIdx.x;
    __shared__ float qp[64];
    __shared__ int selh[8], selw[8];
    if (tid < 64) qp[tid] = q_probe[(size_t)bh * 64 + tid];
    __syncthreads();
    if (tid < 128) {
        int isCol = tid >> 6;
        int x = tid & 63;
        float sv = 0.f;
        if (isCol) {
            for (int d = 0; d < 64; ++d) sv += qp[d] * k_colsum[((size_t)bh * 64 + d) * 64 + x];
        } else {
            for (int d = 0; d < 64; ++d) sv += qp[d] * k_rowsum[((size_t)bh * 64 + x) * 64 + d];
        }
        float v = sv;
        for (int it = 0; it < 8; ++it) {
            float bv = v; int bi = x;
#pragma unroll
            for (int off = 32; off; off >>= 1) {
                float ov = __shfl_xor(bv, off);
                int   oi = __shfl_xor(bi, off);
                if (ov > bv || (ov == bv && oi < bi)) { bv = ov; bi = oi; }
            }
            if (x == 0) { if (isCol) selw[it] = bi; else selh[it] = bi; }
            if (x == bi) v = -3.4e38f;
        }
    }
    __syncthreads();
    for (int idx = tid; idx < 4096; idx += 256) {
        int j = idx >> 6, d = idx & 63;
        int p = selh[j >> 3] * 64 + selw[j & 7];
        k_sel[(size_t)bh * 4096 + idx] = kn[((size_t)bh * 64 + d) * PP + p];
        v_sel[(size_t)bh * 4096 + idx] = vs[((size_t)bh * 64 + d) * PP + p];
    }
}

// ---------------- K5: attention over 64 selected kv positions ----------------
__global__ __launch_bounds__(256) void attn_kernel(const bf16* __restrict__ qn,
                                                   const bf16* __restrict__ k_sel,
                                                   const bf16* __restrict__ v_sel,
                                                   bf16* __restrict__ attn_out) {
    int bh = blockIdx.y;
    int p = blockIdx.x * 256 + threadIdx.x;
    __shared__ float ks[64][65];
    __shared__ float vls[64][65];
    for (int idx = threadIdx.x; idx < 4096; idx += 256) {
        int j = idx >> 6, d = idx & 63;
        ks[j][d]  = b2f(k_sel[(size_t)bh * 4096 + idx]);
        vls[j][d] = b2f(v_sel[(size_t)bh * 4096 + idx]);
    }
    __syncthreads();
    float sim[64];
#pragma unroll
    for (int j = 0; j < 64; ++j) sim[j] = 0.f;
    const bf16* qb = qn + (size_t)bh * 64 * PP + p;
    for (int d = 0; d < 64; ++d) {
        float qd = b2f(qb[(size_t)d * PP]);
#pragma unroll
        for (int j = 0; j < 64; ++j) sim[j] = fmaf(qd, ks[j][d], sim[j]);
    }
    float m = -3.4e38f;
#pragma unroll
    for (int j = 0; j < 64; ++j) m = fmaxf(m, sim[j]);
    float l = 0.f;
#pragma unroll
    for (int j = 0; j < 64; ++j) { sim[j] = __expf(sim[j] - m); l += sim[j]; }
    float rl = 1.f / l;
    bf16* ob = attn_out + (size_t)bh * 64 * PP + p;
    for (int d = 0; d < 64; ++d) {
        float acc = 0.f;
#pragma unroll
        for (int j = 0; j < 64; ++j) acc = fmaf(sim[j], vls[j][d], acc);
        ob[(size_t)d * PP] = f2b(acc * rl);
    }
}

// ---------------- K6: MFMA w_out GEMM (bf16 X, plain) -> y fp32 ----------------
__global__ __launch_bounds__(256) void mfma_out_kernel(const float* __restrict__ Wm,
                                                       const bf16* __restrict__ X,
                                                       float* __restrict__ Y) {
    __shared__ alignas(16) char smraw[16384];   // WH 8K | XH 8K
    char* WH = smraw;
    char* XH = smraw + 8192;

    int b  = blockIdx.z;
    int o0 = blockIdx.x * 64;
    int p0 = blockIdx.y * 64;
    int tid = threadIdx.x;

    int o_s = tid >> 2, segW = tid & 3;
    int p_l = tid & 63, kseg = tid >> 6;
    int l = tid & 63, w = tid >> 6;
    int wm = w >> 1, wn = w & 1;
    int lr = l & 15, lk = l >> 4;

    f32x4 acc[2][2] = {};

    for (int k0 = 0; k0 < INNER; k0 += 64) {
        {
            const float* wg = Wm + (size_t)(o0 + o_s) * INNER + (k0 + segW * 16);
            short8 h0, h1;
#pragma unroll
            for (int i = 0; i < 16; ++i) {
                unsigned short hb = f2h(wg[i]);
                if (i < 8) h0[i] = (short)hb; else h1[i - 8] = (short)hb;
            }
            *(short8*)(WH + sw(o_s, segW * 32))      = h0;
            *(short8*)(WH + sw(o_s, segW * 32 + 16)) = h1;
        }
        {
            const unsigned short* xg = (const unsigned short*)X +
                ((size_t)b * INNER + (k0 + kseg * 16)) * PP + p0 + p_l;
            short8 h0, h1;
#pragma unroll
            for (int i = 0; i < 16; ++i) {
                unsigned short hb = xg[(size_t)i * PP];
                if (i < 8) h0[i] = (short)hb; else h1[i - 8] = (short)hb;
            }
            *(short8*)(XH + sw(p_l, kseg * 32))      = h0;
            *(short8*)(XH + sw(p_l, kseg * 32 + 16)) = h1;
        }
        __syncthreads();
#pragma unroll
        for (int kk = 0; kk < 2; ++kk) {
            int kb = kk * 64 + lk * 16;
            short8 ah[2], bh[2];
#pragma unroll
            for (int f = 0; f < 2; ++f) {
                ah[f] = *(short8*)(WH + sw(wm * 32 + f * 16 + lr, kb));
                bh[f] = *(short8*)(XH + sw(wn * 32 + f * 16 + lr, kb));
            }
#pragma unroll
            for (int fm = 0; fm < 2; ++fm)
#pragma unroll
                for (int fn = 0; fn < 2; ++fn)
                    acc[fm][fn] = __builtin_amdgcn_mfma_f32_16x16x32_bf16(ah[fm], bh[fn], acc[fm][fn], 0, 0, 0);
        }
        __syncthreads();
    }
#pragma unroll
    for (int fm = 0; fm < 2; ++fm)
#pragma unroll
        for (int fn = 0; fn < 2; ++fn)
#pragma unroll
            for (int r = 0; r < 4; ++r)
                Y[((size_t)b * CDIM + o0 + wm * 32 + fm * 16 + lk * 4 + r) * PP
                  + p0 + wn * 32 + fn * 16 + lr] = acc[fm][fn][r];
}

// ---------------- K7: final LN + gamma*out + residual ----------------
__global__ __launch_bounds__(256) void final_ln_kernel(const float* __restrict__ y,
                                                       const float* __restrict__ g,
                                                       const float* __restrict__ bb,
                                                       const float* __restrict__ gamma,
                                                       const float* __restrict__ resid,
                                                       float* __restrict__ out) {
    int b = blockIdx.y;
    int p = blockIdx.x * 256 + threadIdx.x;
    const float* yb = y + (size_t)b * CDIM * PP + p;
    float s = 0.f, sq = 0.f;
    for (int c = 0; c < CDIM; ++c) {
        float v = yb[(size_t)c * PP];
        s += v; sq += v * v;
    }
    float mean = s * (1.f / CDIM);
    float var  = sq * (1.f / CDIM) - mean * mean;
    float rstd = rsqrtf(var + 1e-5f);
    float gm = gamma[0];
    const float* rb = resid + (size_t)b * CDIM * PP + p;
    float* ob = out + (size_t)b * CDIM * PP + p;
    for (int c = 0; c < CDIM; ++c) {
        float v = yb[(size_t)c * PP];
        float xn = (v - mean) * rstd * g[c] + bb[c];
        ob[(size_t)c * PP] = gm * xn + rb[(size_t)c * PP];
    }
}

extern "C" void kernel_launch(void* const* d_in, const int* in_sizes, int n_in,
                              void* d_out, int out_size, void* d_ws, size_t ws_size,
                              hipStream_t stream) {
    const float* query_source = (const float*)d_in[0];
    const float* context      = (const float*)d_in[1];
    const float* cn_g = (const float*)d_in[2];
    const float* cn_b = (const float*)d_in[3];
    const float* qn_g = (const float*)d_in[4];
    const float* qn_b = (const float*)d_in[5];
    const float* on_g = (const float*)d_in[6];
    const float* on_b = (const float*)d_in[7];
    const float* w_kv = (const float*)d_in[8];
    const float* w_q  = (const float*)d_in[9];
    const float* w_out= (const float*)d_in[10];
    const float* gamma= (const float*)d_in[11];
    float* out = (float*)d_out;

    char* ws = (char*)d_ws;
    float* A      = (float*)(ws + 0);           // 32M fp32 staging, later attn_out
    bf16*  attn_o = (bf16*)(ws + 0);
    bf16*  k_n   = (bf16*)(ws + 33554432);      // later y
    float* y     = (float*)(ws + 33554432);
    bf16*  v_s   = (bf16*)(ws + 67108864);
    bf16*  q_n   = (bf16*)(ws + 100663296);
    float* q_probe  = (float*)(ws + 134217728); // zeroed
    float* k_colsum = (float*)(ws + 134234112); // zeroed
    float* k_rowsum = (float*)(ws + 135282688);
    bf16*  k_sel = (bf16*)(ws + 136331264);
    bf16*  v_sel = (bf16*)(ws + 136855552);

    hipMemsetAsync(ws + 134217728, 0, 16384 + 1048576, stream);

    dim3 blk(256);
    ln_in_kernel<<<dim3(16, BB), blk, 0, stream>>>(context, cn_g, cn_b, A);
    mfma_qkv_kernel<<<dim3(16, 64, BB), blk, 0, stream>>>(w_kv, A, k_n, v_s, CDIM, 512, 0,
                                                          k_rowsum, k_colsum, q_probe);
    ln_in_kernel<<<dim3(16, BB), blk, 0, stream>>>(query_source, qn_g, qn_b, A);
    mfma_qkv_kernel<<<dim3(8, 64, BB), blk, 0, stream>>>(w_q, A, q_n, nullptr, CDIM, 512, 1,
                                                         k_rowsum, k_colsum, q_probe);
    select_gather_kernel<<<dim3(64), blk, 0, stream>>>(q_probe, k_rowsum, k_colsum,
                                                       k_n, v_s, k_sel, v_sel);
    attn_kernel<<<dim3(16, NBH), blk, 0, stream>>>(q_n, k_sel, v_sel, attn_o);
    mfma_out_kernel<<<dim3(4, 64, BB), blk, 0, stream>>>(w_out, attn_o, y);
    final_ln_kernel<<<dim3(16, BB), blk, 0, stream>>>(y, on_g, on_b, gamma, query_source, out);
}

// Round 4
// 692.282 us; speedup vs baseline: 1.8458x; 1.0356x over previous
//
#include <hip/hip_runtime.h>
#include <hip/hip_bf16.h>

#define BB 8
#define CDIM 256
#define PP 4096
#define NHEADS 8
#define DHEAD 64
#define INNER 512
#define NBH 64

using bf16 = __hip_bfloat16;
typedef short short8 __attribute__((ext_vector_type(8)));
typedef float f32x4 __attribute__((ext_vector_type(4)));
typedef unsigned short u16;

__device__ __forceinline__ float b2f(bf16 x) { return __bfloat162float(x); }
__device__ __forceinline__ bf16 f2b(float x) { return __float2bfloat16(x); }

__device__ __forceinline__ u16 f2h(float x) {
    union { float f; unsigned u; } c; c.f = x;
    unsigned r = c.u + 0x7FFF + ((c.u >> 16) & 1);
    return (u16)(r >> 16);
}
__device__ __forceinline__ float h2f(u16 h) {
    union { float f; unsigned u; } c; c.u = ((unsigned)h) << 16;
    return c.f;
}

// XOR-swizzled byte offset inside a [64 rows][128 B] LDS tile
__device__ __forceinline__ int sw(int row, int kb) {
    return row * 128 + (kb ^ ((row & 7) << 4));
}

// async global->LDS, 16B per lane; lds base wave-uniform, HW adds lane*16
__device__ __forceinline__ void gload16(const void* g, void* lds) {
    __builtin_amdgcn_global_load_lds((const __attribute__((address_space(1))) void*)g,
                                     (__attribute__((address_space(3))) void*)lds, 16, 0, 0);
}

// XCD-aware remap: the gridDim.x o-tiles sharing one X chunk land on ONE XCD.
// h -> (xcd = h&7, m = h>>3); group g = (m/GS)*8 + xcd; j = m%GS. Bijective when
// total/(8*GS) is integral (64 here for all three GEMMs).
__device__ __forceinline__ void remap(int& o0, int& p0, int& b) {
    unsigned GS = gridDim.x;
    unsigned h = (blockIdx.z * gridDim.y + blockIdx.y) * GS + blockIdx.x;
    unsigned xc = h & 7, m = h >> 3;
    unsigned g = (m / GS) * 8 + xc;
    o0 = (int)(m % GS) * 64;
    p0 = (int)(g & 63) * 64;
    b  = (int)(g >> 6);
}

// ---------------- K0: split weights into bf16 hi/lo ----------------
__global__ __launch_bounds__(256) void wsplit_kernel(const float* __restrict__ W,
                                                     u16* __restrict__ WH,
                                                     u16* __restrict__ WL) {
    int i = blockIdx.x * 256 + threadIdx.x;
    float v = W[i];
    u16 hb = f2h(v);
    WH[i] = hb;
    if (WL) WL[i] = f2h(v - h2f(hb));
}

// ---------------- K1: channel LN -> transposed bf16 hi/lo [b][p][c] ----------------
__global__ __launch_bounds__(256) void ln_split_kernel(const float* __restrict__ x,
                                                       const float* __restrict__ g,
                                                       const float* __restrict__ bb,
                                                       u16* __restrict__ XH,
                                                       u16* __restrict__ XL) {
    int b = blockIdx.y;
    int p0 = blockIdx.x * 64;
    int tid = threadIdx.x;
    int px = tid & 63, cg = tid >> 6;
    __shared__ float red_s[4][64], red_q[4][64], meanv[64], rstdv[64];

    const float* xb = x + (size_t)b * CDIM * PP + p0 + px;
    float s = 0.f, sq = 0.f;
#pragma unroll 8
    for (int i = 0; i < 64; ++i) {
        float v = xb[(size_t)(cg * 64 + i) * PP];
        s += v; sq += v * v;
    }
    red_s[cg][px] = s; red_q[cg][px] = sq;
    __syncthreads();
    if (tid < 64) {
        float ts = red_s[0][tid] + red_s[1][tid] + red_s[2][tid] + red_s[3][tid];
        float tq = red_q[0][tid] + red_q[1][tid] + red_q[2][tid] + red_q[3][tid];
        float mean = ts * (1.f / CDIM);
        float var  = tq * (1.f / CDIM) - mean * mean;
        meanv[tid] = mean;
        rstdv[tid] = rsqrtf(var + 1e-5f);
    }
    __syncthreads();
    float mean = meanv[px], rstd = rstdv[px];
    size_t orow = ((size_t)b * PP + p0 + px) * CDIM;
    for (int c0 = cg * 64; c0 < cg * 64 + 64; c0 += 8) {
        short8 hv, lv;
#pragma unroll
        for (int j = 0; j < 8; ++j) {
            int c = c0 + j;
            float v = xb[(size_t)c * PP];
            float n = (v - mean) * rstd * g[c] + bb[c];
            u16 hb = f2h(n);
            hv[j] = (short)hb;
            lv[j] = (short)f2h(n - h2f(hb));
        }
        *(short8*)(XH + orow + c0) = hv;
        *(short8*)(XL + orow + c0) = lv;
    }
}

// ---------------- K2: MFMA conv1x1 GEMM, bf16x3 from pre-split operands ----------------
__global__ __launch_bounds__(256) void mfma_qkv_kernel(const u16* __restrict__ WH,
                                                       const u16* __restrict__ WL,
                                                       const u16* __restrict__ XH,
                                                       const u16* __restrict__ XL,
                                                       bf16* __restrict__ dstA,
                                                       bf16* __restrict__ dstB,
                                                       int Kdim, int norm_below, int mode,
                                                       float* __restrict__ k_rowsum,
                                                       float* __restrict__ k_colsum,
                                                       float* __restrict__ q_probe) {
    __shared__ alignas(16) char sm[32768];   // AH|AL|BH|BL (8K each), later C[64][65] f32
    __shared__ float red[16][64];
    __shared__ float rinv[64];
    char* AH = sm;
    char* AL = sm + 8192;
    char* BH = sm + 16384;
    char* BL = sm + 24576;
    float* C = (float*)sm;

    int o0, p0, b;
    remap(o0, p0, b);
    int tid = threadIdx.x;
    int l = tid & 63, w = tid >> 6;
    int wm = w >> 1, wn = w & 1;
    int lr = l & 15, lk = l >> 4;
    int r8 = l >> 3;
    int kswz = ((l & 7) * 16) ^ (r8 << 4);   // swizzled source byte within 128B chunk

    f32x4 acc[2][2] = {};

    for (int k0 = 0; k0 < Kdim; k0 += 64) {
#pragma unroll
        for (int j = 0; j < 2; ++j) {
            int rb = w * 16 + j * 8;
            int row = rb + r8;
            size_t aoff = ((size_t)(o0 + row) * Kdim + k0) * 2 + kswz;
            size_t boff = (((size_t)b * PP + p0 + row) * Kdim + k0) * 2 + kswz;
            gload16((const char*)WH + aoff, AH + rb * 128);
            gload16((const char*)WL + aoff, AL + rb * 128);
            gload16((const char*)XH + boff, BH + rb * 128);
            gload16((const char*)XL + boff, BL + rb * 128);
        }
        __syncthreads();
#pragma unroll
        for (int kk = 0; kk < 2; ++kk) {
            int kb = kk * 64 + lk * 16;
            short8 ah[2], al[2], bh[2], bl[2];
#pragma unroll
            for (int f = 0; f < 2; ++f) {
                ah[f] = *(short8*)(AH + sw(wm * 32 + f * 16 + lr, kb));
                al[f] = *(short8*)(AL + sw(wm * 32 + f * 16 + lr, kb));
                bh[f] = *(short8*)(BH + sw(wn * 32 + f * 16 + lr, kb));
                bl[f] = *(short8*)(BL + sw(wn * 32 + f * 16 + lr, kb));
            }
#pragma unroll
            for (int fm = 0; fm < 2; ++fm)
#pragma unroll
                for (int fn = 0; fn < 2; ++fn) {
                    acc[fm][fn] = __builtin_amdgcn_mfma_f32_16x16x32_bf16(ah[fm], bh[fn], acc[fm][fn], 0, 0, 0);
                    acc[fm][fn] = __builtin_amdgcn_mfma_f32_16x16x32_bf16(ah[fm], bl[fn], acc[fm][fn], 0, 0, 0);
                    acc[fm][fn] = __builtin_amdgcn_mfma_f32_16x16x32_bf16(al[fm], bh[fn], acc[fm][fn], 0, 0, 0);
                }
        }
        __syncthreads();
    }

    // ---- dump fp32 C tile to LDS (verified layout) ----
#pragma unroll
    for (int fm = 0; fm < 2; ++fm)
#pragma unroll
        for (int fn = 0; fn < 2; ++fn)
#pragma unroll
            for (int r = 0; r < 4; ++r)
                C[(wm * 32 + fm * 16 + lk * 4 + r) * 65 + wn * 32 + fn * 16 + lr] = acc[fm][fn][r];
    __syncthreads();

    int tx = tid & 15, ty = tid >> 4;
    float a2[4][4];
#pragma unroll
    for (int i = 0; i < 4; ++i)
#pragma unroll
        for (int j = 0; j < 4; ++j)
            a2[i][j] = C[(ty * 4 + i) * 65 + tx * 4 + j];

    // ---- verified epilogue (Round 2/3) ----
    bool donorm = (o0 < norm_below);
    if (donorm) {
#pragma unroll
        for (int j = 0; j < 4; ++j) {
            float sj = 0.f;
#pragma unroll
            for (int i = 0; i < 4; ++i) sj += a2[i][j] * a2[i][j];
            red[ty][tx * 4 + j] = sj;
        }
        __syncthreads();
        if (tid < 64) {
            float s = 0.f;
#pragma unroll
            for (int yy = 0; yy < 16; ++yy) s += red[yy][tid];
            rinv[tid] = 1.f / fmaxf(sqrtf(s), 1e-12f);
        }
        __syncthreads();
#pragma unroll
        for (int i = 0; i < 4; ++i)
#pragma unroll
            for (int j = 0; j < 4; ++j)
                a2[i][j] *= rinv[tx * 4 + j];
    }

    int oo = donorm ? o0 : (o0 - norm_below);
    bf16* dest = donorm ? dstA : dstB;
#pragma unroll
    for (int i = 0; i < 4; ++i) {
        int oc = oo + ty * 4 + i;
        int bh = b * NHEADS + (oc >> 6);
        int d  = oc & 63;
        bf16* drow = dest + ((size_t)bh * DHEAD + d) * PP + p0;
#pragma unroll
        for (int j = 0; j < 4; ++j) drow[tx * 4 + j] = f2b(a2[i][j]);
    }

    if (donorm) {
        int bh = b * NHEADS + (o0 >> 6);
        int h  = p0 >> 6;
        float part[4];
#pragma unroll
        for (int i = 0; i < 4; ++i) {
            float s = 0.f;
#pragma unroll
            for (int j = 0; j < 4; ++j)
                s += (mode == 0) ? fabsf(a2[i][j]) : a2[i][j];
            part[i] = s;
        }
        __syncthreads();
#pragma unroll
        for (int i = 0; i < 4; ++i) red[tx][ty * 4 + i] = part[i];
        __syncthreads();
        if (tid < 64) {
            float s = 0.f;
#pragma unroll
            for (int t = 0; t < 16; ++t) s += red[t][tid];
            if (mode == 0) k_rowsum[((size_t)bh * 64 + h) * 64 + tid] = s;
            else           atomicAdd(&q_probe[(size_t)bh * 64 + tid], s);
        }
        if (mode == 0) {
#pragma unroll
            for (int i = 0; i < 4; ++i)
#pragma unroll
                for (int j = 0; j < 4; ++j)
                    atomicAdd(&k_colsum[((size_t)bh * 64 + (ty * 4 + i)) * 64 + (tx * 4 + j)],
                              fabsf(a2[i][j]));
        }
    }
}

// ---------------- K4: scores, top-8 rows/cols, gather ----------------
__global__ __launch_bounds__(256) void select_gather_kernel(const float* __restrict__ q_probe,
                                                            const float* __restrict__ k_rowsum,
                                                            const float* __restrict__ k_colsum,
                                                            const bf16* __restrict__ kn,
                                                            const bf16* __restrict__ vs,
                                                            bf16* __restrict__ k_sel,
                                                            bf16* __restrict__ v_sel) {
    int bh = blockIdx.x;
    int tid = threadIdx.x;
    __shared__ float qp[64];
    __shared__ int selh[8], selw[8];
    if (tid < 64) qp[tid] = q_probe[(size_t)bh * 64 + tid];
    __syncthreads();
    if (tid < 128) {
        int isCol = tid >> 6;
        int x = tid & 63;
        float sv = 0.f;
        if (isCol) {
            for (int d = 0; d < 64; ++d) sv += qp[d] * k_colsum[((size_t)bh * 64 + d) * 64 + x];
        } else {
            for (int d = 0; d < 64; ++d) sv += qp[d] * k_rowsum[((size_t)bh * 64 + x) * 64 + d];
        }
        float v = sv;
        for (int it = 0; it < 8; ++it) {
            float bv = v; int bi = x;
#pragma unroll
            for (int off = 32; off; off >>= 1) {
                float ov = __shfl_xor(bv, off);
                int   oi = __shfl_xor(bi, off);
                if (ov > bv || (ov == bv && oi < bi)) { bv = ov; bi = oi; }
            }
            if (x == 0) { if (isCol) selw[it] = bi; else selh[it] = bi; }
            if (x == bi) v = -3.4e38f;
        }
    }
    __syncthreads();
    for (int idx = tid; idx < 4096; idx += 256) {
        int j = idx >> 6, d = idx & 63;
        int p = selh[j >> 3] * 64 + selw[j & 7];
        k_sel[(size_t)bh * 4096 + idx] = kn[((size_t)bh * 64 + d) * PP + p];
        v_sel[(size_t)bh * 4096 + idx] = vs[((size_t)bh * 64 + d) * PP + p];
    }
}

// ---------------- K5: attention; writes transposed [b][p][inner] bf16 ----------------
__global__ __launch_bounds__(256) void attn_kernel(const bf16* __restrict__ qn,
                                                   const bf16* __restrict__ k_sel,
                                                   const bf16* __restrict__ v_sel,
                                                   u16* __restrict__ attn_t) {
    int bh = blockIdx.y;
    int p = blockIdx.x * 256 + threadIdx.x;
    __shared__ float ks[64][65];
    __shared__ float vls[64][65];
    for (int idx = threadIdx.x; idx < 4096; idx += 256) {
        int j = idx >> 6, d = idx & 63;
        ks[j][d]  = b2f(k_sel[(size_t)bh * 4096 + idx]);
        vls[j][d] = b2f(v_sel[(size_t)bh * 4096 + idx]);
    }
    __syncthreads();
    float sim[64];
#pragma unroll
    for (int j = 0; j < 64; ++j) sim[j] = 0.f;
    const bf16* qb = qn + (size_t)bh * 64 * PP + p;
    for (int d = 0; d < 64; ++d) {
        float qd = b2f(qb[(size_t)d * PP]);
#pragma unroll
        for (int j = 0; j < 64; ++j) sim[j] = fmaf(qd, ks[j][d], sim[j]);
    }
    float m = -3.4e38f;
#pragma unroll
    for (int j = 0; j < 64; ++j) m = fmaxf(m, sim[j]);
    float l = 0.f;
#pragma unroll
    for (int j = 0; j < 64; ++j) { sim[j] = __expf(sim[j] - m); l += sim[j]; }
    float rl = 1.f / l;
    u16* ob = attn_t + ((size_t)(bh >> 3) * PP + p) * INNER + (bh & 7) * 64;
    for (int d0 = 0; d0 < 64; d0 += 8) {
        short8 pk;
#pragma unroll
        for (int jj = 0; jj < 8; ++jj) {
            int d = d0 + jj;
            float acc = 0.f;
#pragma unroll
            for (int j = 0; j < 64; ++j) acc = fmaf(sim[j], vls[j][d], acc);
            pk[jj] = (short)f2h(acc * rl);
        }
        *(short8*)(ob + d0) = pk;
    }
}

// ---------------- K6: MFMA w_out GEMM (pre-split bf16) -> y fp32 ----------------
__global__ __launch_bounds__(256) void mfma_out_kernel(const u16* __restrict__ WHp,
                                                       const u16* __restrict__ Xt,
                                                       float* __restrict__ Y) {
    __shared__ alignas(16) char sm[16384];   // AH 8K | BH 8K
    char* AH = sm;
    char* BH = sm + 8192;

    int o0, p0, b;
    remap(o0, p0, b);
    int tid = threadIdx.x;
    int l = tid & 63, w = tid >> 6;
    int wm = w >> 1, wn = w & 1;
    int lr = l & 15, lk = l >> 4;
    int r8 = l >> 3;
    int kswz = ((l & 7) * 16) ^ (r8 << 4);

    f32x4 acc[2][2] = {};

    for (int k0 = 0; k0 < INNER; k0 += 64) {
#pragma unroll
        for (int j = 0; j < 2; ++j) {
            int rb = w * 16 + j * 8;
            int row = rb + r8;
            size_t aoff = ((size_t)(o0 + row) * INNER + k0) * 2 + kswz;
            size_t boff = (((size_t)b * PP + p0 + row) * INNER + k0) * 2 + kswz;
            gload16((const char*)WHp + aoff, AH + rb * 128);
            gload16((const char*)Xt + boff, BH + rb * 128);
        }
        __syncthreads();
#pragma unroll
        for (int kk = 0; kk < 2; ++kk) {
            int kb = kk * 64 + lk * 16;
            short8 ah[2], bh[2];
#pragma unroll
            for (int f = 0; f < 2; ++f) {
                ah[f] = *(short8*)(AH + sw(wm * 32 + f * 16 + lr, kb));
                bh[f] = *(short8*)(BH + sw(wn * 32 + f * 16 + lr, kb));
            }
#pragma unroll
            for (int fm = 0; fm < 2; ++fm)
#pragma unroll
                for (int fn = 0; fn < 2; ++fn)
                    acc[fm][fn] = __builtin_amdgcn_mfma_f32_16x16x32_bf16(ah[fm], bh[fn], acc[fm][fn], 0, 0, 0);
        }
        __syncthreads();
    }
#pragma unroll
    for (int fm = 0; fm < 2; ++fm)
#pragma unroll
        for (int fn = 0; fn < 2; ++fn)
#pragma unroll
            for (int r = 0; r < 4; ++r)
                Y[((size_t)b * CDIM + o0 + wm * 32 + fm * 16 + lk * 4 + r) * PP
                  + p0 + wn * 32 + fn * 16 + lr] = acc[fm][fn][r];
}

// ---------------- K7: final LN + gamma*out + residual ----------------
__global__ __launch_bounds__(256) void final_ln_kernel(const float* __restrict__ y,
                                                       const float* __restrict__ g,
                                                       const float* __restrict__ bb,
                                                       const float* __restrict__ gamma,
                                                       const float* __restrict__ resid,
                                                       float* __restrict__ out) {
    int b = blockIdx.y;
    int p = blockIdx.x * 256 + threadIdx.x;
    const float* yb = y + (size_t)b * CDIM * PP + p;
    float s = 0.f, sq = 0.f;
    for (int c = 0; c < CDIM; ++c) {
        float v = yb[(size_t)c * PP];
        s += v; sq += v * v;
    }
    float mean = s * (1.f / CDIM);
    float var  = sq * (1.f / CDIM) - mean * mean;
    float rstd = rsqrtf(var + 1e-5f);
    float gm = gamma[0];
    const float* rb = resid + (size_t)b * CDIM * PP + p;
    float* ob = out + (size_t)b * CDIM * PP + p;
    for (int c = 0; c < CDIM; ++c) {
        float v = yb[(size_t)c * PP];
        float xn = (v - mean) * rstd * g[c] + bb[c];
        ob[(size_t)c * PP] = gm * xn + rb[(size_t)c * PP];
    }
}

extern "C" void kernel_launch(void* const* d_in, const int* in_sizes, int n_in,
                              void* d_out, int out_size, void* d_ws, size_t ws_size,
                              hipStream_t stream) {
    const float* query_source = (const float*)d_in[0];
    const float* context      = (const float*)d_in[1];
    const float* cn_g = (const float*)d_in[2];
    const float* cn_b = (const float*)d_in[3];
    const float* qn_g = (const float*)d_in[4];
    const float* qn_b = (const float*)d_in[5];
    const float* on_g = (const float*)d_in[6];
    const float* on_b = (const float*)d_in[7];
    const float* w_kv = (const float*)d_in[8];
    const float* w_q  = (const float*)d_in[9];
    const float* w_out= (const float*)d_in[10];
    const float* gamma= (const float*)d_in[11];
    float* out = (float*)d_out;

    char* ws = (char*)d_ws;
    // [0,32M): XH_t(16M)+XL_t(16M) for ctx, then qs; later attn_t (32M)
    u16*  XHt   = (u16*)(ws + 0);
    u16*  XLt   = (u16*)(ws + 16777216);
    u16*  attn_t= (u16*)(ws + 0);
    // [32M,64M): k_n bf16; later y fp32
    bf16*  k_n  = (bf16*)(ws + 33554432);
    float* y    = (float*)(ws + 33554432);
    bf16*  v_s  = (bf16*)(ws + 67108864);     // [64M,96M)
    // [96M,128M): WkvH(512K)+WkvL(512K) early, then q_n bf16 (32M)
    u16*  WkvH  = (u16*)(ws + 100663296);
    u16*  WkvL  = (u16*)(ws + 100663296 + 524288);
    bf16* q_n   = (bf16*)(ws + 100663296);
    float* q_probe  = (float*)(ws + 134217728); // 16K, zeroed
    float* k_colsum = (float*)(ws + 134234112); // 1M, zeroed
    float* k_rowsum = (float*)(ws + 135282688); // 1M; later WoutH (256K)
    u16*  WoutH = (u16*)(ws + 135282688);
    // [136.3M,137.3M): WqH(512K)+WqL(512K) early, then k_sel/v_sel
    u16*  WqH   = (u16*)(ws + 136331264);
    u16*  WqL   = (u16*)(ws + 136855552);
    bf16* k_sel = (bf16*)(ws + 136331264);
    bf16* v_sel = (bf16*)(ws + 136855552);

    hipMemsetAsync(ws + 134217728, 0, 16384 + 1048576, stream);

    dim3 blk(256);
    wsplit_kernel<<<dim3(1024), blk, 0, stream>>>(w_kv, WkvH, WkvL);
    wsplit_kernel<<<dim3(512), blk, 0, stream>>>(w_q, WqH, WqL);
    ln_split_kernel<<<dim3(64, BB), blk, 0, stream>>>(context, cn_g, cn_b, XHt, XLt);
    mfma_qkv_kernel<<<dim3(16, 64, BB), blk, 0, stream>>>(WkvH, WkvL, XHt, XLt, k_n, v_s,
                                                          CDIM, 512, 0,
                                                          k_rowsum, k_colsum, q_probe);
    ln_split_kernel<<<dim3(64, BB), blk, 0, stream>>>(query_source, qn_g, qn_b, XHt, XLt);
    mfma_qkv_kernel<<<dim3(8, 64, BB), blk, 0, stream>>>(WqH, WqL, XHt, XLt, q_n, nullptr,
                                                         CDIM, 512, 1,
                                                         k_rowsum, k_colsum, q_probe);
    select_gather_kernel<<<dim3(64), blk, 0, stream>>>(q_probe, k_rowsum, k_colsum,
                                                       k_n, v_s, k_sel, v_sel);
    wsplit_kernel<<<dim3(512), blk, 0, stream>>>(w_out, WoutH, nullptr);
    attn_kernel<<<dim3(16, NBH), blk, 0, stream>>>(q_n, k_sel, v_sel, attn_t);
    mfma_out_kernel<<<dim3(4, 64, BB), blk, 0, stream>>>(WoutH, attn_t, y);
    final_ln_kernel<<<dim3(16, BB), blk, 0, stream>>>(y, on_g, on_b, gamma, query_source, out);
}

// Round 5
// 526.765 us; speedup vs baseline: 2.4258x; 1.3142x over previous
//
#include <hip/hip_runtime.h>
#include <hip/hip_bf16.h>

#define BB 8
#define CDIM 256
#define PP 4096
#define NHEADS 8
#define DHEAD 64
#define INNER 512
#define NBH 64

using bf16 = __hip_bfloat16;
typedef short short8 __attribute__((ext_vector_type(8)));
typedef float f32x4 __attribute__((ext_vector_type(4)));
typedef unsigned short u16;

__device__ __forceinline__ float b2f(bf16 x) { return __bfloat162float(x); }
__device__ __forceinline__ bf16 f2b(float x) { return __float2bfloat16(x); }

__device__ __forceinline__ u16 f2h(float x) {
    union { float f; unsigned u; } c; c.f = x;
    unsigned r = c.u + 0x7FFF + ((c.u >> 16) & 1);
    return (u16)(r >> 16);
}
__device__ __forceinline__ float h2f(u16 h) {
    union { float f; unsigned u; } c; c.u = ((unsigned)h) << 16;
    return c.f;
}

// XOR-swizzled byte offset inside a [64 rows][128 B] LDS tile
__device__ __forceinline__ int sw(int row, int kb) {
    return row * 128 + (kb ^ ((row & 7) << 4));
}

// async global->LDS, 16B per lane; lds base wave-uniform, HW adds lane*16
__device__ __forceinline__ void gload16(const void* g, void* lds) {
    __builtin_amdgcn_global_load_lds((const __attribute__((address_space(1))) void*)g,
                                     (__attribute__((address_space(3))) void*)lds, 16, 0, 0);
}

// XCD-aware remap (verified round 4: FETCH 137->21 MB): o-tiles sharing an X chunk
// land on one XCD. Bijective for all grids used here.
__device__ __forceinline__ void remap(int& o0, int& p0, int& b) {
    unsigned GS = gridDim.x;
    unsigned h = (blockIdx.z * gridDim.y + blockIdx.y) * GS + blockIdx.x;
    unsigned xc = h & 7, m = h >> 3;
    unsigned g = (m / GS) * 8 + xc;
    o0 = (int)(m % GS) * 64;
    p0 = (int)(g & 63) * 64;
    b  = (int)(g >> 6);
}

// ---------------- K0: split weights into bf16 hi/lo ----------------
__global__ __launch_bounds__(256) void wsplit_kernel(const float* __restrict__ W,
                                                     u16* __restrict__ WH,
                                                     u16* __restrict__ WL) {
    int i = blockIdx.x * 256 + threadIdx.x;
    float v = W[i];
    u16 hb = f2h(v);
    WH[i] = hb;
    if (WL) WL[i] = f2h(v - h2f(hb));
}

// ---------------- K1: channel LN -> transposed bf16 hi/lo [b][p][c] ----------------
__global__ __launch_bounds__(256) void ln_split_kernel(const float* __restrict__ x,
                                                       const float* __restrict__ g,
                                                       const float* __restrict__ bb,
                                                       u16* __restrict__ XH,
                                                       u16* __restrict__ XL) {
    int b = blockIdx.y;
    int p0 = blockIdx.x * 64;
    int tid = threadIdx.x;
    int px = tid & 63, cg = tid >> 6;
    __shared__ float red_s[4][64], red_q[4][64], meanv[64], rstdv[64];

    const float* xb = x + (size_t)b * CDIM * PP + p0 + px;
    float s = 0.f, sq = 0.f;
#pragma unroll 8
    for (int i = 0; i < 64; ++i) {
        float v = xb[(size_t)(cg * 64 + i) * PP];
        s += v; sq += v * v;
    }
    red_s[cg][px] = s; red_q[cg][px] = sq;
    __syncthreads();
    if (tid < 64) {
        float ts = red_s[0][tid] + red_s[1][tid] + red_s[2][tid] + red_s[3][tid];
        float tq = red_q[0][tid] + red_q[1][tid] + red_q[2][tid] + red_q[3][tid];
        float mean = ts * (1.f / CDIM);
        float var  = tq * (1.f / CDIM) - mean * mean;
        meanv[tid] = mean;
        rstdv[tid] = rsqrtf(var + 1e-5f);
    }
    __syncthreads();
    float mean = meanv[px], rstd = rstdv[px];
    size_t orow = ((size_t)b * PP + p0 + px) * CDIM;
    for (int c0 = cg * 64; c0 < cg * 64 + 64; c0 += 8) {
        short8 hv, lv;
#pragma unroll
        for (int j = 0; j < 8; ++j) {
            int c = c0 + j;
            float v = xb[(size_t)c * PP];
            float n = (v - mean) * rstd * g[c] + bb[c];
            u16 hb = f2h(n);
            hv[j] = (short)hb;
            lv[j] = (short)f2h(n - h2f(hb));
        }
        *(short8*)(XH + orow + c0) = hv;
        *(short8*)(XL + orow + c0) = lv;
    }
}

// ---------------- K2: MFMA conv1x1 GEMM, bf16x3, NO-ATOMIC score epilogue ----------------
// mode 0 (kv): normed tiles (K) -> colscore_part[bh][h][w] = sum_d qp[d]*|k_n[d,w]| (direct store)
// mode 1 (q):  all normed -> qprobe_part[bh][h][d] = sum_{w in tile} q_n[d,w] (direct store)
__global__ __launch_bounds__(256) void mfma_qkv_kernel(const u16* __restrict__ WH,
                                                       const u16* __restrict__ WL,
                                                       const u16* __restrict__ XH,
                                                       const u16* __restrict__ XL,
                                                       bf16* __restrict__ dstA,
                                                       bf16* __restrict__ dstB,
                                                       int Kdim, int norm_below, int mode,
                                                       float* __restrict__ part_out,
                                                       const float* __restrict__ q_probe) {
    __shared__ alignas(16) char sm[32768];   // AH|AL|BH|BL (8K each), later C[64][65] f32
    __shared__ float red[16][64];
    __shared__ float rinv[64];
    __shared__ float qp_s[64];
    char* AH = sm;
    char* AL = sm + 8192;
    char* BH = sm + 16384;
    char* BL = sm + 24576;
    float* C = (float*)sm;

    int o0, p0, b;
    remap(o0, p0, b);
    int tid = threadIdx.x;
    int l = tid & 63, w = tid >> 6;
    int wm = w >> 1, wn = w & 1;
    int lr = l & 15, lk = l >> 4;
    int r8 = l >> 3;
    int kswz = ((l & 7) * 16) ^ (r8 << 4);

    bool donorm = (o0 < norm_below);
    if (mode == 0 && donorm && tid < 64)
        qp_s[tid] = q_probe[(size_t)(b * NHEADS + (o0 >> 6)) * 64 + tid];

    f32x4 acc[2][2] = {};

    for (int k0 = 0; k0 < Kdim; k0 += 64) {
#pragma unroll
        for (int j = 0; j < 2; ++j) {
            int rb = w * 16 + j * 8;
            int row = rb + r8;
            size_t aoff = ((size_t)(o0 + row) * Kdim + k0) * 2 + kswz;
            size_t boff = (((size_t)b * PP + p0 + row) * Kdim + k0) * 2 + kswz;
            gload16((const char*)WH + aoff, AH + rb * 128);
            gload16((const char*)WL + aoff, AL + rb * 128);
            gload16((const char*)XH + boff, BH + rb * 128);
            gload16((const char*)XL + boff, BL + rb * 128);
        }
        __syncthreads();
#pragma unroll
        for (int kk = 0; kk < 2; ++kk) {
            int kb = kk * 64 + lk * 16;
            short8 ah[2], al[2], bh[2], bl[2];
#pragma unroll
            for (int f = 0; f < 2; ++f) {
                ah[f] = *(short8*)(AH + sw(wm * 32 + f * 16 + lr, kb));
                al[f] = *(short8*)(AL + sw(wm * 32 + f * 16 + lr, kb));
                bh[f] = *(short8*)(BH + sw(wn * 32 + f * 16 + lr, kb));
                bl[f] = *(short8*)(BL + sw(wn * 32 + f * 16 + lr, kb));
            }
#pragma unroll
            for (int fm = 0; fm < 2; ++fm)
#pragma unroll
                for (int fn = 0; fn < 2; ++fn) {
                    acc[fm][fn] = __builtin_amdgcn_mfma_f32_16x16x32_bf16(ah[fm], bh[fn], acc[fm][fn], 0, 0, 0);
                    acc[fm][fn] = __builtin_amdgcn_mfma_f32_16x16x32_bf16(ah[fm], bl[fn], acc[fm][fn], 0, 0, 0);
                    acc[fm][fn] = __builtin_amdgcn_mfma_f32_16x16x32_bf16(al[fm], bh[fn], acc[fm][fn], 0, 0, 0);
                }
        }
        __syncthreads();
    }

    // ---- dump fp32 C tile to LDS (verified layout) ----
#pragma unroll
    for (int fm = 0; fm < 2; ++fm)
#pragma unroll
        for (int fn = 0; fn < 2; ++fn)
#pragma unroll
            for (int r = 0; r < 4; ++r)
                C[(wm * 32 + fm * 16 + lk * 4 + r) * 65 + wn * 32 + fn * 16 + lr] = acc[fm][fn][r];
    __syncthreads();

    int tx = tid & 15, ty = tid >> 4;
    float a2[4][4];
#pragma unroll
    for (int i = 0; i < 4; ++i)
#pragma unroll
        for (int j = 0; j < 4; ++j)
            a2[i][j] = C[(ty * 4 + i) * 65 + tx * 4 + j];

    // ---- l2norm (verified) ----
    if (donorm) {
#pragma unroll
        for (int j = 0; j < 4; ++j) {
            float sj = 0.f;
#pragma unroll
            for (int i = 0; i < 4; ++i) sj += a2[i][j] * a2[i][j];
            red[ty][tx * 4 + j] = sj;
        }
        __syncthreads();
        if (tid < 64) {
            float s = 0.f;
#pragma unroll
            for (int yy = 0; yy < 16; ++yy) s += red[yy][tid];
            rinv[tid] = 1.f / fmaxf(sqrtf(s), 1e-12f);
        }
        __syncthreads();
#pragma unroll
        for (int i = 0; i < 4; ++i)
#pragma unroll
            for (int j = 0; j < 4; ++j)
                a2[i][j] *= rinv[tx * 4 + j];
    }

    int oo = donorm ? o0 : (o0 - norm_below);
    bf16* dest = donorm ? dstA : dstB;
#pragma unroll
    for (int i = 0; i < 4; ++i) {
        int oc = oo + ty * 4 + i;
        int bh = b * NHEADS + (oc >> 6);
        int d  = oc & 63;
        bf16* drow = dest + ((size_t)bh * DHEAD + d) * PP + p0;
#pragma unroll
        for (int j = 0; j < 4; ++j) drow[tx * 4 + j] = f2b(a2[i][j]);
    }

    // ---- atomic-free score partials ----
    if (donorm) {
        int bh = b * NHEADS + (o0 >> 6);
        int h  = p0 >> 6;                       // one tile == one spatial row
        if (mode == 0) {
            // c_j = sum_d qp[d]*|k_n[d][w=tx*4+j]|
            float cj[4];
#pragma unroll
            for (int j = 0; j < 4; ++j) {
                float s = 0.f;
#pragma unroll
                for (int i = 0; i < 4; ++i) s += qp_s[ty * 4 + i] * fabsf(a2[i][j]);
                cj[j] = s;
            }
#pragma unroll
            for (int j = 0; j < 4; ++j) red[ty][tx * 4 + j] = cj[j];
            __syncthreads();
            if (tid < 64) {
                float s = 0.f;
#pragma unroll
                for (int t = 0; t < 16; ++t) s += red[t][tid];
                part_out[((size_t)bh * 64 + h) * 64 + tid] = s;   // colscore_part
            }
        } else {
            // qprobe partial: sum over this tile's 64 w per d
            float part[4];
#pragma unroll
            for (int i = 0; i < 4; ++i) {
                float s = 0.f;
#pragma unroll
                for (int j = 0; j < 4; ++j) s += a2[i][j];
                part[i] = s;
            }
#pragma unroll
            for (int i = 0; i < 4; ++i) red[tx][ty * 4 + i] = part[i];
            __syncthreads();
            if (tid < 64) {
                float s = 0.f;
#pragma unroll
                for (int t = 0; t < 16; ++t) s += red[t][tid];
                part_out[((size_t)bh * 64 + h) * 64 + tid] = s;   // qprobe_part
            }
        }
    }
}

// ---------------- K3: q_probe[bh][d] = sum_h qprobe_part[bh][h][d] ----------------
__global__ __launch_bounds__(64) void qreduce_kernel(const float* __restrict__ part,
                                                     float* __restrict__ q_probe) {
    int bh = blockIdx.x, d = threadIdx.x;
    float s = 0.f;
    for (int h = 0; h < 64; ++h) s += part[((size_t)bh * 64 + h) * 64 + d];
    q_probe[(size_t)bh * 64 + d] = s;
}

// ---------------- K4: scores from colscore_part, top-8, gather ----------------
__global__ __launch_bounds__(256) void select_gather_kernel(const float* __restrict__ colpart,
                                                            const bf16* __restrict__ kn,
                                                            const bf16* __restrict__ vs,
                                                            bf16* __restrict__ k_sel,
                                                            bf16* __restrict__ v_sel) {
    int bh = blockIdx.x;
    int tid = threadIdx.x;
    __shared__ float M[64][65];
    __shared__ int selh[8], selw[8];
    for (int i = tid; i < 4096; i += 256) M[i >> 6][i & 63] = colpart[(size_t)bh * 4096 + i];
    __syncthreads();
    if (tid < 128) {
        int isCol = tid >> 6;
        int x = tid & 63;
        float sv = 0.f;
        if (isCol) { for (int h = 0; h < 64; ++h) sv += M[h][x]; }   // score_c[w]
        else       { for (int w = 0; w < 64; ++w) sv += M[x][w]; }   // score_r[h]
        float v = sv;
        for (int it = 0; it < 8; ++it) {
            float bv = v; int bi = x;
#pragma unroll
            for (int off = 32; off; off >>= 1) {
                float ov = __shfl_xor(bv, off);
                int   oi = __shfl_xor(bi, off);
                if (ov > bv || (ov == bv && oi < bi)) { bv = ov; bi = oi; }
            }
            if (x == 0) { if (isCol) selw[it] = bi; else selh[it] = bi; }
            if (x == bi) v = -3.4e38f;
        }
    }
    __syncthreads();
    for (int idx = tid; idx < 4096; idx += 256) {
        int j = idx >> 6, d = idx & 63;
        int p = selh[j >> 3] * 64 + selw[j & 7];
        k_sel[(size_t)bh * 4096 + idx] = kn[((size_t)bh * 64 + d) * PP + p];
        v_sel[(size_t)bh * 4096 + idx] = vs[((size_t)bh * 64 + d) * PP + p];
    }
}

// ---------------- K5: attention; writes transposed [b][p][inner] bf16 ----------------
__global__ __launch_bounds__(256) void attn_kernel(const bf16* __restrict__ qn,
                                                   const bf16* __restrict__ k_sel,
                                                   const bf16* __restrict__ v_sel,
                                                   u16* __restrict__ attn_t) {
    int bh = blockIdx.y;
    int p = blockIdx.x * 256 + threadIdx.x;
    __shared__ float ks[64][65];
    __shared__ float vls[64][65];
    for (int idx = threadIdx.x; idx < 4096; idx += 256) {
        int j = idx >> 6, d = idx & 63;
        ks[j][d]  = b2f(k_sel[(size_t)bh * 4096 + idx]);
        vls[j][d] = b2f(v_sel[(size_t)bh * 4096 + idx]);
    }
    __syncthreads();
    float sim[64];
#pragma unroll
    for (int j = 0; j < 64; ++j) sim[j] = 0.f;
    const bf16* qb = qn + (size_t)bh * 64 * PP + p;
    for (int d = 0; d < 64; ++d) {
        float qd = b2f(qb[(size_t)d * PP]);
#pragma unroll
        for (int j = 0; j < 64; ++j) sim[j] = fmaf(qd, ks[j][d], sim[j]);
    }
    float m = -3.4e38f;
#pragma unroll
    for (int j = 0; j < 64; ++j) m = fmaxf(m, sim[j]);
    float l = 0.f;
#pragma unroll
    for (int j = 0; j < 64; ++j) { sim[j] = __expf(sim[j] - m); l += sim[j]; }
    float rl = 1.f / l;
    u16* ob = attn_t + ((size_t)(bh >> 3) * PP + p) * INNER + (bh & 7) * 64;
    for (int d0 = 0; d0 < 64; d0 += 8) {
        short8 pk;
#pragma unroll
        for (int jj = 0; jj < 8; ++jj) {
            int d = d0 + jj;
            float acc = 0.f;
#pragma unroll
            for (int j = 0; j < 64; ++j) acc = fmaf(sim[j], vls[j][d], acc);
            pk[jj] = (short)f2h(acc * rl);
        }
        *(short8*)(ob + d0) = pk;
    }
}

// ---------------- K6: MFMA w_out GEMM (pre-split bf16) -> y fp32 ----------------
__global__ __launch_bounds__(256) void mfma_out_kernel(const u16* __restrict__ WHp,
                                                       const u16* __restrict__ Xt,
                                                       float* __restrict__ Y) {
    __shared__ alignas(16) char sm[16384];   // AH 8K | BH 8K
    char* AH = sm;
    char* BH = sm + 8192;

    int o0, p0, b;
    remap(o0, p0, b);
    int tid = threadIdx.x;
    int l = tid & 63, w = tid >> 6;
    int wm = w >> 1, wn = w & 1;
    int lr = l & 15, lk = l >> 4;
    int r8 = l >> 3;
    int kswz = ((l & 7) * 16) ^ (r8 << 4);

    f32x4 acc[2][2] = {};

    for (int k0 = 0; k0 < INNER; k0 += 64) {
#pragma unroll
        for (int j = 0; j < 2; ++j) {
            int rb = w * 16 + j * 8;
            int row = rb + r8;
            size_t aoff = ((size_t)(o0 + row) * INNER + k0) * 2 + kswz;
            size_t boff = (((size_t)b * PP + p0 + row) * INNER + k0) * 2 + kswz;
            gload16((const char*)WHp + aoff, AH + rb * 128);
            gload16((const char*)Xt + boff, BH + rb * 128);
        }
        __syncthreads();
#pragma unroll
        for (int kk = 0; kk < 2; ++kk) {
            int kb = kk * 64 + lk * 16;
            short8 ah[2], bh[2];
#pragma unroll
            for (int f = 0; f < 2; ++f) {
                ah[f] = *(short8*)(AH + sw(wm * 32 + f * 16 + lr, kb));
                bh[f] = *(short8*)(BH + sw(wn * 32 + f * 16 + lr, kb));
            }
#pragma unroll
            for (int fm = 0; fm < 2; ++fm)
#pragma unroll
                for (int fn = 0; fn < 2; ++fn)
                    acc[fm][fn] = __builtin_amdgcn_mfma_f32_16x16x32_bf16(ah[fm], bh[fn], acc[fm][fn], 0, 0, 0);
        }
        __syncthreads();
    }
#pragma unroll
    for (int fm = 0; fm < 2; ++fm)
#pragma unroll
        for (int fn = 0; fn < 2; ++fn)
#pragma unroll
            for (int r = 0; r < 4; ++r)
                Y[((size_t)b * CDIM + o0 + wm * 32 + fm * 16 + lk * 4 + r) * PP
                  + p0 + wn * 32 + fn * 16 + lr] = acc[fm][fn][r];
}

// ---------------- K7: final LN + gamma*out + residual ----------------
__global__ __launch_bounds__(256) void final_ln_kernel(const float* __restrict__ y,
                                                       const float* __restrict__ g,
                                                       const float* __restrict__ bb,
                                                       const float* __restrict__ gamma,
                                                       const float* __restrict__ resid,
                                                       float* __restrict__ out) {
    int b = blockIdx.y;
    int p = blockIdx.x * 256 + threadIdx.x;
    const float* yb = y + (size_t)b * CDIM * PP + p;
    float s = 0.f, sq = 0.f;
    for (int c = 0; c < CDIM; ++c) {
        float v = yb[(size_t)c * PP];
        s += v; sq += v * v;
    }
    float mean = s * (1.f / CDIM);
    float var  = sq * (1.f / CDIM) - mean * mean;
    float rstd = rsqrtf(var + 1e-5f);
    float gm = gamma[0];
    const float* rb = resid + (size_t)b * CDIM * PP + p;
    float* ob = out + (size_t)b * CDIM * PP + p;
    for (int c = 0; c < CDIM; ++c) {
        float v = yb[(size_t)c * PP];
        float xn = (v - mean) * rstd * g[c] + bb[c];
        ob[(size_t)c * PP] = gm * xn + rb[(size_t)c * PP];
    }
}

extern "C" void kernel_launch(void* const* d_in, const int* in_sizes, int n_in,
                              void* d_out, int out_size, void* d_ws, size_t ws_size,
                              hipStream_t stream) {
    const float* query_source = (const float*)d_in[0];
    const float* context      = (const float*)d_in[1];
    const float* cn_g = (const float*)d_in[2];
    const float* cn_b = (const float*)d_in[3];
    const float* qn_g = (const float*)d_in[4];
    const float* qn_b = (const float*)d_in[5];
    const float* on_g = (const float*)d_in[6];
    const float* on_b = (const float*)d_in[7];
    const float* w_kv = (const float*)d_in[8];
    const float* w_q  = (const float*)d_in[9];
    const float* w_out= (const float*)d_in[10];
    const float* gamma= (const float*)d_in[11];
    float* out = (float*)d_out;

    char* ws = (char*)d_ws;
    // [0,32M): XHt(16M)+XLt(16M) (qs phase, then ctx phase); later attn_t (32M)
    u16*  XHt    = (u16*)(ws + 0);
    u16*  XLt    = (u16*)(ws + 16777216);
    u16*  attn_t = (u16*)(ws + 0);
    // [32M,64M): k_n bf16; later y fp32
    bf16*  k_n  = (bf16*)(ws + 33554432);
    float* y    = (float*)(ws + 33554432);
    bf16*  v_s  = (bf16*)(ws + 67108864);      // [64M,96M)
    bf16*  q_n  = (bf16*)(ws + 100663296);     // [96M,128M)
    // [128M..): small buffers with disjoint lifetimes
    u16*  WqH   = (u16*)(ws + 134217728);      // 512K (dead after q GEMM)
    u16*  WqL   = (u16*)(ws + 134742016);      // 512K
    bf16* k_sel = (bf16*)(ws + 134217728);     // aliases WqH (select >> q GEMM)
    bf16* v_sel = (bf16*)(ws + 134742016);     // aliases WqL
    u16*  WkvH  = (u16*)(ws + 135266304);      // 512K (dead after kv GEMM)
    u16*  WkvL  = (u16*)(ws + 135790592);      // 512K
    u16*  WoutH = (u16*)(ws + 135266304);      // 256K, aliases WkvH
    float* qprobe_part   = (float*)(ws + 136314880); // 1M (dead after qreduce)
    float* colscore_part = (float*)(ws + 136314880); // 1M, aliases qprobe_part
    float* q_probe       = (float*)(ws + 137363456); // 16K (end: 137,379,840)

    dim3 blk(256);
    // ---- q pipeline (produces q_probe before kv GEMM) ----
    wsplit_kernel<<<dim3(512), blk, 0, stream>>>(w_q, WqH, WqL);
    ln_split_kernel<<<dim3(64, BB), blk, 0, stream>>>(query_source, qn_g, qn_b, XHt, XLt);
    mfma_qkv_kernel<<<dim3(8, 64, BB), blk, 0, stream>>>(WqH, WqL, XHt, XLt, q_n, nullptr,
                                                         CDIM, 512, 1, qprobe_part, nullptr);
    qreduce_kernel<<<dim3(64), dim3(64), 0, stream>>>(qprobe_part, q_probe);
    // ---- kv pipeline ----
    wsplit_kernel<<<dim3(1024), blk, 0, stream>>>(w_kv, WkvH, WkvL);
    ln_split_kernel<<<dim3(64, BB), blk, 0, stream>>>(context, cn_g, cn_b, XHt, XLt);
    mfma_qkv_kernel<<<dim3(16, 64, BB), blk, 0, stream>>>(WkvH, WkvL, XHt, XLt, k_n, v_s,
                                                          CDIM, 512, 0, colscore_part, q_probe);
    // ---- select / attention / output ----
    select_gather_kernel<<<dim3(64), blk, 0, stream>>>(colscore_part, k_n, v_s, k_sel, v_sel);
    wsplit_kernel<<<dim3(512), blk, 0, stream>>>(w_out, WoutH, nullptr);
    attn_kernel<<<dim3(16, NBH), blk, 0, stream>>>(q_n, k_sel, v_sel, attn_t);
    mfma_out_kernel<<<dim3(4, 64, BB), blk, 0, stream>>>(WoutH, attn_t, y);
    final_ln_kernel<<<dim3(16, BB), blk, 0, stream>>>(y, on_g, on_b, gamma, query_source, out);
}

// Round 6
// 390.909 us; speedup vs baseline: 3.2689x; 1.3475x over previous
//
#include <hip/hip_runtime.h>
#include <hip/hip_bf16.h>

#define BB 8
#define CDIM 256
#define PP 4096
#define NHEADS 8
#define DHEAD 64
#define INNER 512
#define NBH 64

using bf16 = __hip_bfloat16;
typedef short short8 __attribute__((ext_vector_type(8)));
typedef float f32x4 __attribute__((ext_vector_type(4)));
typedef unsigned short u16;

__device__ __forceinline__ float b2f(bf16 x) { return __bfloat162float(x); }
__device__ __forceinline__ bf16 f2b(float x) { return __float2bfloat16(x); }

__device__ __forceinline__ u16 f2h(float x) {
    union { float f; unsigned u; } c; c.f = x;
    unsigned r = c.u + 0x7FFF + ((c.u >> 16) & 1);
    return (u16)(r >> 16);
}
__device__ __forceinline__ float h2f(u16 h) {
    union { float f; unsigned u; } c; c.u = ((unsigned)h) << 16;
    return c.f;
}

// XOR-swizzled byte offset inside a [64 rows][128 B] LDS tile
__device__ __forceinline__ int sw(int row, int kb) {
    return row * 128 + (kb ^ ((row & 7) << 4));
}

// async global->LDS, 16B per lane; lds base wave-uniform, HW adds lane*16
__device__ __forceinline__ void gload16(const void* g, void* lds) {
    __builtin_amdgcn_global_load_lds((const __attribute__((address_space(1))) void*)g,
                                     (__attribute__((address_space(3))) void*)lds, 16, 0, 0);
}

// XCD-aware remap (verified round 4: FETCH 137->21 MB)
__device__ __forceinline__ void remap(int& o0, int& p0, int& b) {
    unsigned GS = gridDim.x;
    unsigned h = (blockIdx.z * gridDim.y + blockIdx.y) * GS + blockIdx.x;
    unsigned xc = h & 7, m = h >> 3;
    unsigned g = (m / GS) * 8 + xc;
    o0 = (int)(m % GS) * 64;
    p0 = (int)(g & 63) * 64;
    b  = (int)(g >> 6);
}

// ---------------- K0: split weights into bf16 hi/lo ----------------
__global__ __launch_bounds__(256) void wsplit_kernel(const float* __restrict__ W,
                                                     u16* __restrict__ WH,
                                                     u16* __restrict__ WL) {
    int i = blockIdx.x * 256 + threadIdx.x;
    float v = W[i];
    u16 hb = f2h(v);
    WH[i] = hb;
    if (WL) WL[i] = f2h(v - h2f(hb));
}

// ---------------- K1: channel LN -> transposed bf16 hi/lo [b][p][c] ----------------
__global__ __launch_bounds__(256) void ln_split_kernel(const float* __restrict__ x,
                                                       const float* __restrict__ g,
                                                       const float* __restrict__ bb,
                                                       u16* __restrict__ XH,
                                                       u16* __restrict__ XL) {
    int b = blockIdx.y;
    int p0 = blockIdx.x * 64;
    int tid = threadIdx.x;
    int px = tid & 63, cg = tid >> 6;
    __shared__ float red_s[4][64], red_q[4][64], meanv[64], rstdv[64];

    const float* xb = x + (size_t)b * CDIM * PP + p0 + px;
    float s = 0.f, sq = 0.f;
#pragma unroll 8
    for (int i = 0; i < 64; ++i) {
        float v = xb[(size_t)(cg * 64 + i) * PP];
        s += v; sq += v * v;
    }
    red_s[cg][px] = s; red_q[cg][px] = sq;
    __syncthreads();
    if (tid < 64) {
        float ts = red_s[0][tid] + red_s[1][tid] + red_s[2][tid] + red_s[3][tid];
        float tq = red_q[0][tid] + red_q[1][tid] + red_q[2][tid] + red_q[3][tid];
        float mean = ts * (1.f / CDIM);
        float var  = tq * (1.f / CDIM) - mean * mean;
        meanv[tid] = mean;
        rstdv[tid] = rsqrtf(var + 1e-5f);
    }
    __syncthreads();
    float mean = meanv[px], rstd = rstdv[px];
    size_t orow = ((size_t)b * PP + p0 + px) * CDIM;
    for (int c0 = cg * 64; c0 < cg * 64 + 64; c0 += 8) {
        short8 hv, lv;
#pragma unroll
        for (int j = 0; j < 8; ++j) {
            int c = c0 + j;
            float v = xb[(size_t)c * PP];
            float n = (v - mean) * rstd * g[c] + bb[c];
            u16 hb = f2h(n);
            hv[j] = (short)hb;
            lv[j] = (short)f2h(n - h2f(hb));
        }
        *(short8*)(XH + orow + c0) = hv;
        *(short8*)(XL + orow + c0) = lv;
    }
}

// ---------------- K2: MFMA conv1x1 GEMM, bf16x3, atomic-free epilogue ----------------
// mode 0 (kv): K tiles -> folded d-major store + colscore_part; V -> folded store.
// mode 1 (q):  transposed store q_t[bh][p][d] + qprobe_part.
__global__ __launch_bounds__(256) void mfma_qkv_kernel(const u16* __restrict__ WH,
                                                       const u16* __restrict__ WL,
                                                       const u16* __restrict__ XH,
                                                       const u16* __restrict__ XL,
                                                       u16* __restrict__ dstA,
                                                       u16* __restrict__ dstB,
                                                       int Kdim, int norm_below, int mode,
                                                       float* __restrict__ part_out,
                                                       const float* __restrict__ q_probe) {
    __shared__ alignas(16) char sm[32768];   // AH|AL|BH|BL (8K each), later C[64][65] f32
    __shared__ float red[16][64];
    __shared__ float rinv[64];
    __shared__ float qp_s[64];
    char* AH = sm;
    char* AL = sm + 8192;
    char* BH = sm + 16384;
    char* BL = sm + 24576;
    float* C = (float*)sm;

    int o0, p0, b;
    remap(o0, p0, b);
    int tid = threadIdx.x;
    int l = tid & 63, w = tid >> 6;
    int wm = w >> 1, wn = w & 1;
    int lr = l & 15, lk = l >> 4;
    int r8 = l >> 3;
    int kswz = ((l & 7) * 16) ^ (r8 << 4);

    bool donorm = (o0 < norm_below);
    if (mode == 0 && donorm && tid < 64)
        qp_s[tid] = q_probe[(size_t)(b * NHEADS + (o0 >> 6)) * 64 + tid];

    f32x4 acc[2][2] = {};

    for (int k0 = 0; k0 < Kdim; k0 += 64) {
#pragma unroll
        for (int j = 0; j < 2; ++j) {
            int rb = w * 16 + j * 8;
            int row = rb + r8;
            size_t aoff = ((size_t)(o0 + row) * Kdim + k0) * 2 + kswz;
            size_t boff = (((size_t)b * PP + p0 + row) * Kdim + k0) * 2 + kswz;
            gload16((const char*)WH + aoff, AH + rb * 128);
            gload16((const char*)WL + aoff, AL + rb * 128);
            gload16((const char*)XH + boff, BH + rb * 128);
            gload16((const char*)XL + boff, BL + rb * 128);
        }
        __syncthreads();
#pragma unroll
        for (int kk = 0; kk < 2; ++kk) {
            int kb = kk * 64 + lk * 16;
            short8 ah[2], al[2], bh[2], bl[2];
#pragma unroll
            for (int f = 0; f < 2; ++f) {
                ah[f] = *(short8*)(AH + sw(wm * 32 + f * 16 + lr, kb));
                al[f] = *(short8*)(AL + sw(wm * 32 + f * 16 + lr, kb));
                bh[f] = *(short8*)(BH + sw(wn * 32 + f * 16 + lr, kb));
                bl[f] = *(short8*)(BL + sw(wn * 32 + f * 16 + lr, kb));
            }
#pragma unroll
            for (int fm = 0; fm < 2; ++fm)
#pragma unroll
                for (int fn = 0; fn < 2; ++fn) {
                    acc[fm][fn] = __builtin_amdgcn_mfma_f32_16x16x32_bf16(ah[fm], bh[fn], acc[fm][fn], 0, 0, 0);
                    acc[fm][fn] = __builtin_amdgcn_mfma_f32_16x16x32_bf16(ah[fm], bl[fn], acc[fm][fn], 0, 0, 0);
                    acc[fm][fn] = __builtin_amdgcn_mfma_f32_16x16x32_bf16(al[fm], bh[fn], acc[fm][fn], 0, 0, 0);
                }
        }
        __syncthreads();
    }

    // ---- dump fp32 C tile to LDS (verified layout) ----
#pragma unroll
    for (int fm = 0; fm < 2; ++fm)
#pragma unroll
        for (int fn = 0; fn < 2; ++fn)
#pragma unroll
            for (int r = 0; r < 4; ++r)
                C[(wm * 32 + fm * 16 + lk * 4 + r) * 65 + wn * 32 + fn * 16 + lr] = acc[fm][fn][r];
    __syncthreads();

    int tx = tid & 15, ty = tid >> 4;
    float a2[4][4];
#pragma unroll
    for (int i = 0; i < 4; ++i)
#pragma unroll
        for (int j = 0; j < 4; ++j)
            a2[i][j] = C[(ty * 4 + i) * 65 + tx * 4 + j];

    // ---- l2norm (verified) ----
    if (donorm) {
#pragma unroll
        for (int j = 0; j < 4; ++j) {
            float sj = 0.f;
#pragma unroll
            for (int i = 0; i < 4; ++i) sj += a2[i][j] * a2[i][j];
            red[ty][tx * 4 + j] = sj;
        }
        __syncthreads();
        if (tid < 64) {
            float s = 0.f;
#pragma unroll
            for (int yy = 0; yy < 16; ++yy) s += red[yy][tid];
            rinv[tid] = 1.f / fmaxf(sqrtf(s), 1e-12f);
        }
        __syncthreads();
#pragma unroll
        for (int i = 0; i < 4; ++i)
#pragma unroll
            for (int j = 0; j < 4; ++j)
                a2[i][j] *= rinv[tx * 4 + j];
    }

    if (mode == 1) {
        // transposed normalized store: q_t[(bh*PP + p)*64 + d], from intact C tile
        int p_l = tid & 63, og = tid >> 6;
        float rv = rinv[p_l];
        u16* qrow = dstA + ((size_t)(b * NHEADS + (o0 >> 6)) * PP + p0 + p_l) * 64 + og * 16;
        short8 s0, s1;
#pragma unroll
        for (int i = 0; i < 8; ++i) s0[i] = (short)f2h(C[(og * 16 + i) * 65 + p_l] * rv);
#pragma unroll
        for (int i = 0; i < 8; ++i) s1[i] = (short)f2h(C[(og * 16 + 8 + i) * 65 + p_l] * rv);
        *(short8*)qrow = s0;
        *(short8*)(qrow + 8) = s1;
    } else {
        int oo = donorm ? o0 : (o0 - norm_below);
        u16* dest = donorm ? dstA : dstB;
#pragma unroll
        for (int i = 0; i < 4; ++i) {
            int oc = oo + ty * 4 + i;
            int bh = b * NHEADS + (oc >> 6);
            int d  = oc & 63;
            u16* drow = dest + ((size_t)bh * DHEAD + d) * PP + p0;
#pragma unroll
            for (int j = 0; j < 4; ++j) drow[tx * 4 + j] = f2h(a2[i][j]);
        }
    }

    // ---- atomic-free score partials ----
    if (donorm) {
        int bh = b * NHEADS + (o0 >> 6);
        int h  = p0 >> 6;                       // one tile == one spatial row
        if (mode == 0) {
            float cj[4];
#pragma unroll
            for (int j = 0; j < 4; ++j) {
                float s = 0.f;
#pragma unroll
                for (int i = 0; i < 4; ++i) s += qp_s[ty * 4 + i] * fabsf(a2[i][j]);
                cj[j] = s;
            }
            __syncthreads();
#pragma unroll
            for (int j = 0; j < 4; ++j) red[ty][tx * 4 + j] = cj[j];
            __syncthreads();
            if (tid < 64) {
                float s = 0.f;
#pragma unroll
                for (int t = 0; t < 16; ++t) s += red[t][tid];
                part_out[((size_t)bh * 64 + h) * 64 + tid] = s;   // colscore_part
            }
        } else {
            float part[4];
#pragma unroll
            for (int i = 0; i < 4; ++i) {
                float s = 0.f;
#pragma unroll
                for (int j = 0; j < 4; ++j) s += a2[i][j];
                part[i] = s;
            }
            __syncthreads();
#pragma unroll
            for (int i = 0; i < 4; ++i) red[tx][ty * 4 + i] = part[i];
            __syncthreads();
            if (tid < 64) {
                float s = 0.f;
#pragma unroll
                for (int t = 0; t < 16; ++t) s += red[t][tid];
                part_out[((size_t)bh * 64 + h) * 64 + tid] = s;   // qprobe_part
            }
        }
    }
}

// ---------------- K3: q_probe[bh][d] = sum_h qprobe_part[bh][h][d] ----------------
__global__ __launch_bounds__(64) void qreduce_kernel(const float* __restrict__ part,
                                                     float* __restrict__ q_probe) {
    int bh = blockIdx.x, d = threadIdx.x;
    float s = 0.f;
    for (int h = 0; h < 64; ++h) s += part[((size_t)bh * 64 + h) * 64 + d];
    q_probe[(size_t)bh * 64 + d] = s;
}

// ---------------- K4: scores from colscore_part, top-8, gather ----------------
// k_sel[bh][j][d]; v_selt[bh][d][j] (transposed for PV B-operand)
__global__ __launch_bounds__(256) void select_gather_kernel(const float* __restrict__ colpart,
                                                            const u16* __restrict__ kn,
                                                            const u16* __restrict__ vs,
                                                            u16* __restrict__ k_sel,
                                                            u16* __restrict__ v_selt) {
    int bh = blockIdx.x;
    int tid = threadIdx.x;
    __shared__ float M[64][65];
    __shared__ int selh[8], selw[8];
    for (int i = tid; i < 4096; i += 256) M[i >> 6][i & 63] = colpart[(size_t)bh * 4096 + i];
    __syncthreads();
    if (tid < 128) {
        int isCol = tid >> 6;
        int x = tid & 63;
        float sv = 0.f;
        if (isCol) { for (int h = 0; h < 64; ++h) sv += M[h][x]; }
        else       { for (int w = 0; w < 64; ++w) sv += M[x][w]; }
        float v = sv;
        for (int it = 0; it < 8; ++it) {
            float bv = v; int bi = x;
#pragma unroll
            for (int off = 32; off; off >>= 1) {
                float ov = __shfl_xor(bv, off);
                int   oi = __shfl_xor(bi, off);
                if (ov > bv || (ov == bv && oi < bi)) { bv = ov; bi = oi; }
            }
            if (x == 0) { if (isCol) selw[it] = bi; else selh[it] = bi; }
            if (x == bi) v = -3.4e38f;
        }
    }
    __syncthreads();
    for (int idx = tid; idx < 4096; idx += 256) {
        int j = idx >> 6, d = idx & 63;
        int p = selh[j >> 3] * 64 + selw[j & 7];
        u16 kv = kn[((size_t)bh * 64 + d) * PP + p];
        u16 vv = vs[((size_t)bh * 64 + d) * PP + p];
        k_sel[(size_t)bh * 4096 + j * 64 + d]  = kv;
        v_selt[(size_t)bh * 4096 + d * 64 + j] = vv;
    }
}

// ---------------- K5: MFMA attention; writes transposed [b][p][inner] ----------------
__global__ __launch_bounds__(256) void attn_mfma_kernel(const u16* __restrict__ qt,
                                                        const u16* __restrict__ ksel,
                                                        const u16* __restrict__ vselt,
                                                        u16* __restrict__ attn_t) {
    __shared__ alignas(16) char AQ[8192];    // Q tile, then P tile
    __shared__ alignas(16) char BK[8192];    // K tile
    __shared__ alignas(16) char BV[8192];    // V^T tile
    __shared__ float SIM[64 * 68];
    int bh = blockIdx.y;
    int p0 = blockIdx.x * 64;
    int b = bh >> 3, h = bh & 7;
    int tid = threadIdx.x;
    int l = tid & 63, w = tid >> 6;
    int wm = w >> 1, wn = w & 1;
    int lr = l & 15, lk = l >> 4;
    int r8 = l >> 3;
    int kswz = ((l & 7) * 16) ^ (r8 << 4);

#pragma unroll
    for (int j = 0; j < 2; ++j) {
        int rb = w * 16 + j * 8;
        int row = rb + r8;
        gload16((const char*)qt + ((size_t)bh * PP + p0 + row) * 128 + kswz, AQ + rb * 128);
        gload16((const char*)ksel + ((size_t)bh * 64 + row) * 128 + kswz, BK + rb * 128);
        gload16((const char*)vselt + ((size_t)bh * 64 + row) * 128 + kswz, BV + rb * 128);
    }
    __syncthreads();

    // MFMA1: sim[p][j] = sum_d Q[p][d] K[j][d]
    f32x4 acc[2][2] = {};
#pragma unroll
    for (int kk = 0; kk < 2; ++kk) {
        int kb = kk * 64 + lk * 16;
        short8 av[2], bv[2];
#pragma unroll
        for (int f = 0; f < 2; ++f) {
            av[f] = *(short8*)(AQ + sw(wm * 32 + f * 16 + lr, kb));
            bv[f] = *(short8*)(BK + sw(wn * 32 + f * 16 + lr, kb));
        }
#pragma unroll
        for (int fm = 0; fm < 2; ++fm)
#pragma unroll
            for (int fn = 0; fn < 2; ++fn)
                acc[fm][fn] = __builtin_amdgcn_mfma_f32_16x16x32_bf16(av[fm], bv[fn], acc[fm][fn], 0, 0, 0);
    }
#pragma unroll
    for (int fm = 0; fm < 2; ++fm)
#pragma unroll
        for (int fn = 0; fn < 2; ++fn)
#pragma unroll
            for (int r = 0; r < 4; ++r)
                SIM[(wm * 32 + fm * 16 + lk * 4 + r) * 68 + wn * 32 + fn * 16 + lr] = acc[fm][fn][r];
    __syncthreads();

    // softmax over j (4 lanes per row p), P*(1/l) -> bf16 into AQ (swizzled)
    {
        int p = tid >> 2, qd = tid & 3;
        const float* srow = &SIM[p * 68 + qd * 16];
        float v[16];
#pragma unroll
        for (int jj = 0; jj < 16; ++jj) v[jj] = srow[jj];
        float m = v[0];
#pragma unroll
        for (int jj = 1; jj < 16; ++jj) m = fmaxf(m, v[jj]);
        m = fmaxf(m, __shfl_xor(m, 1));
        m = fmaxf(m, __shfl_xor(m, 2));
        float s = 0.f;
#pragma unroll
        for (int jj = 0; jj < 16; ++jj) { v[jj] = __expf(v[jj] - m); s += v[jj]; }
        s += __shfl_xor(s, 1);
        s += __shfl_xor(s, 2);
        float rl = 1.f / s;
        short8 h0, h1;
#pragma unroll
        for (int jj = 0; jj < 8; ++jj) {
            h0[jj] = (short)f2h(v[jj] * rl);
            h1[jj] = (short)f2h(v[8 + jj] * rl);
        }
        *(short8*)(AQ + sw(p, qd * 32)) = h0;
        *(short8*)(AQ + sw(p, qd * 32 + 16)) = h1;
    }
    __syncthreads();

    // MFMA2: out[p][d] = sum_j P[p][j] V^T[d][j]
    f32x4 acc2[2][2] = {};
#pragma unroll
    for (int kk = 0; kk < 2; ++kk) {
        int kb = kk * 64 + lk * 16;
        short8 av[2], bv[2];
#pragma unroll
        for (int f = 0; f < 2; ++f) {
            av[f] = *(short8*)(AQ + sw(wm * 32 + f * 16 + lr, kb));
            bv[f] = *(short8*)(BV + sw(wn * 32 + f * 16 + lr, kb));
        }
#pragma unroll
        for (int fm = 0; fm < 2; ++fm)
#pragma unroll
            for (int fn = 0; fn < 2; ++fn)
                acc2[fm][fn] = __builtin_amdgcn_mfma_f32_16x16x32_bf16(av[fm], bv[fn], acc2[fm][fn], 0, 0, 0);
    }
    u16* ob = attn_t + ((size_t)b * PP + p0) * INNER + h * 64;
#pragma unroll
    for (int fm = 0; fm < 2; ++fm)
#pragma unroll
        for (int fn = 0; fn < 2; ++fn)
#pragma unroll
            for (int r = 0; r < 4; ++r)
                ob[(size_t)(wm * 32 + fm * 16 + lk * 4 + r) * INNER + wn * 32 + fn * 16 + lr]
                    = f2h(acc2[fm][fn][r]);
}

// ---------------- K6: MFMA w_out GEMM (pre-split bf16) -> y fp32 ----------------
__global__ __launch_bounds__(256) void mfma_out_kernel(const u16* __restrict__ WHp,
                                                       const u16* __restrict__ Xt,
                                                       float* __restrict__ Y) {
    __shared__ alignas(16) char sm[16384];   // AH 8K | BH 8K
    char* AH = sm;
    char* BH = sm + 8192;

    int o0, p0, b;
    remap(o0, p0, b);
    int tid = threadIdx.x;
    int l = tid & 63, w = tid >> 6;
    int wm = w >> 1, wn = w & 1;
    int lr = l & 15, lk = l >> 4;
    int r8 = l >> 3;
    int kswz = ((l & 7) * 16) ^ (r8 << 4);

    f32x4 acc[2][2] = {};

    for (int k0 = 0; k0 < INNER; k0 += 64) {
#pragma unroll
        for (int j = 0; j < 2; ++j) {
            int rb = w * 16 + j * 8;
            int row = rb + r8;
            size_t aoff = ((size_t)(o0 + row) * INNER + k0) * 2 + kswz;
            size_t boff = (((size_t)b * PP + p0 + row) * INNER + k0) * 2 + kswz;
            gload16((const char*)WHp + aoff, AH + rb * 128);
            gload16((const char*)Xt + boff, BH + rb * 128);
        }
        __syncthreads();
#pragma unroll
        for (int kk = 0; kk < 2; ++kk) {
            int kb = kk * 64 + lk * 16;
            short8 ah[2], bh[2];
#pragma unroll
            for (int f = 0; f < 2; ++f) {
                ah[f] = *(short8*)(AH + sw(wm * 32 + f * 16 + lr, kb));
                bh[f] = *(short8*)(BH + sw(wn * 32 + f * 16 + lr, kb));
            }
#pragma unroll
            for (int fm = 0; fm < 2; ++fm)
#pragma unroll
                for (int fn = 0; fn < 2; ++fn)
                    acc[fm][fn] = __builtin_amdgcn_mfma_f32_16x16x32_bf16(ah[fm], bh[fn], acc[fm][fn], 0, 0, 0);
        }
        __syncthreads();
    }
#pragma unroll
    for (int fm = 0; fm < 2; ++fm)
#pragma unroll
        for (int fn = 0; fn < 2; ++fn)
#pragma unroll
            for (int r = 0; r < 4; ++r)
                Y[((size_t)b * CDIM + o0 + wm * 32 + fm * 16 + lk * 4 + r) * PP
                  + p0 + wn * 32 + fn * 16 + lr] = acc[fm][fn][r];
}

// ---------------- K7: final LN + gamma*out + residual ----------------
__global__ __launch_bounds__(256) void final_ln_kernel(const float* __restrict__ y,
                                                       const float* __restrict__ g,
                                                       const float* __restrict__ bb,
                                                       const float* __restrict__ gamma,
                                                       const float* __restrict__ resid,
                                                       float* __restrict__ out) {
    int b = blockIdx.y;
    int p = blockIdx.x * 256 + threadIdx.x;
    const float* yb = y + (size_t)b * CDIM * PP + p;
    float s = 0.f, sq = 0.f;
    for (int c = 0; c < CDIM; ++c) {
        float v = yb[(size_t)c * PP];
        s += v; sq += v * v;
    }
    float mean = s * (1.f / CDIM);
    float var  = sq * (1.f / CDIM) - mean * mean;
    float rstd = rsqrtf(var + 1e-5f);
    float gm = gamma[0];
    const float* rb = resid + (size_t)b * CDIM * PP + p;
    float* ob = out + (size_t)b * CDIM * PP + p;
    for (int c = 0; c < CDIM; ++c) {
        float v = yb[(size_t)c * PP];
        float xn = (v - mean) * rstd * g[c] + bb[c];
        ob[(size_t)c * PP] = gm * xn + rb[(size_t)c * PP];
    }
}

extern "C" void kernel_launch(void* const* d_in, const int* in_sizes, int n_in,
                              void* d_out, int out_size, void* d_ws, size_t ws_size,
                              hipStream_t stream) {
    const float* query_source = (const float*)d_in[0];
    const float* context      = (const float*)d_in[1];
    const float* cn_g = (const float*)d_in[2];
    const float* cn_b = (const float*)d_in[3];
    const float* qn_g = (const float*)d_in[4];
    const float* qn_b = (const float*)d_in[5];
    const float* on_g = (const float*)d_in[6];
    const float* on_b = (const float*)d_in[7];
    const float* w_kv = (const float*)d_in[8];
    const float* w_q  = (const float*)d_in[9];
    const float* w_out= (const float*)d_in[10];
    const float* gamma= (const float*)d_in[11];
    float* out = (float*)d_out;

    char* ws = (char*)d_ws;
    // [0,32M): XHt(16M)+XLt(16M) (qs phase, then ctx phase); later attn_t (32M)
    u16*  XHt    = (u16*)(ws + 0);
    u16*  XLt    = (u16*)(ws + 16777216);
    u16*  attn_t = (u16*)(ws + 0);
    // [32M,64M): k_n bf16; later y fp32
    u16*   k_n  = (u16*)(ws + 33554432);
    float* y    = (float*)(ws + 33554432);
    u16*   v_s  = (u16*)(ws + 67108864);       // [64M,96M)
    u16*   q_t  = (u16*)(ws + 100663296);      // [96M,128M) transposed q [bh][p][d]
    // [128M..): small buffers with disjoint lifetimes
    u16*  WqH   = (u16*)(ws + 134217728);      // 512K (dead after q GEMM)
    u16*  WqL   = (u16*)(ws + 134742016);      // 512K
    u16*  k_sel = (u16*)(ws + 134217728);      // aliases WqH
    u16*  v_selt= (u16*)(ws + 134742016);      // aliases WqL
    u16*  WkvH  = (u16*)(ws + 135266304);      // 512K (dead after kv GEMM)
    u16*  WkvL  = (u16*)(ws + 135790592);      // 512K
    u16*  WoutH = (u16*)(ws + 135266304);      // 256K, aliases WkvH
    float* qprobe_part   = (float*)(ws + 136314880); // 1M (dead after qreduce)
    float* colscore_part = (float*)(ws + 136314880); // 1M, aliases qprobe_part
    float* q_probe       = (float*)(ws + 137363456); // 16K

    dim3 blk(256);
    // ---- q pipeline (produces q_probe before kv GEMM) ----
    wsplit_kernel<<<dim3(512), blk, 0, stream>>>(w_q, WqH, WqL);
    ln_split_kernel<<<dim3(64, BB), blk, 0, stream>>>(query_source, qn_g, qn_b, XHt, XLt);
    mfma_qkv_kernel<<<dim3(8, 64, BB), blk, 0, stream>>>(WqH, WqL, XHt, XLt, q_t, nullptr,
                                                         CDIM, 512, 1, qprobe_part, nullptr);
    qreduce_kernel<<<dim3(64), dim3(64), 0, stream>>>(qprobe_part, q_probe);
    // ---- kv pipeline ----
    wsplit_kernel<<<dim3(1024), blk, 0, stream>>>(w_kv, WkvH, WkvL);
    ln_split_kernel<<<dim3(64, BB), blk, 0, stream>>>(context, cn_g, cn_b, XHt, XLt);
    mfma_qkv_kernel<<<dim3(16, 64, BB), blk, 0, stream>>>(WkvH, WkvL, XHt, XLt, k_n, v_s,
                                                          CDIM, 512, 0, colscore_part, q_probe);
    // ---- select / attention / output ----
    select_gather_kernel<<<dim3(64), blk, 0, stream>>>(colscore_part, k_n, v_s, k_sel, v_selt);
    wsplit_kernel<<<dim3(512), blk, 0, stream>>>(w_out, WoutH, nullptr);
    attn_mfma_kernel<<<dim3(64, NBH), blk, 0, stream>>>(q_t, k_sel, v_selt, attn_t);
    mfma_out_kernel<<<dim3(4, 64, BB), blk, 0, stream>>>(WoutH, attn_t, y);
    final_ln_kernel<<<dim3(16, BB), blk, 0, stream>>>(y, on_g, on_b, gamma, query_source, out);
}

// Round 7
// 383.057 us; speedup vs baseline: 3.3359x; 1.0205x over previous
//
#include <hip/hip_runtime.h>
#include <hip/hip_bf16.h>

#define BB 8
#define CDIM 256
#define PP 4096
#define NHEADS 8
#define DHEAD 64
#define INNER 512
#define NBH 64

using bf16 = __hip_bfloat16;
typedef short short8 __attribute__((ext_vector_type(8)));
typedef short short4v __attribute__((ext_vector_type(4)));
typedef float f32x4 __attribute__((ext_vector_type(4)));
typedef unsigned short u16;

__device__ __forceinline__ float b2f(bf16 x) { return __bfloat162float(x); }
__device__ __forceinline__ bf16 f2b(float x) { return __float2bfloat16(x); }

__device__ __forceinline__ u16 f2h(float x) {
    union { float f; unsigned u; } c; c.f = x;
    unsigned r = c.u + 0x7FFF + ((c.u >> 16) & 1);
    return (u16)(r >> 16);
}
__device__ __forceinline__ float h2f(u16 h) {
    union { float f; unsigned u; } c; c.u = ((unsigned)h) << 16;
    return c.f;
}

// XOR-swizzled byte offset inside a [64 rows][128 B] LDS tile
__device__ __forceinline__ int sw(int row, int kb) {
    return row * 128 + (kb ^ ((row & 7) << 4));
}

// async global->LDS, 16B per lane; lds base wave-uniform, HW adds lane*16
__device__ __forceinline__ void gload16(const void* g, void* lds) {
    __builtin_amdgcn_global_load_lds((const __attribute__((address_space(1))) void*)g,
                                     (__attribute__((address_space(3))) void*)lds, 16, 0, 0);
}

// XCD-aware remap (verified round 4: FETCH 137->21 MB)
__device__ __forceinline__ void remap(int& o0, int& p0, int& b) {
    unsigned GS = gridDim.x;
    unsigned h = (blockIdx.z * gridDim.y + blockIdx.y) * GS + blockIdx.x;
    unsigned xc = h & 7, m = h >> 3;
    unsigned g = (m / GS) * 8 + xc;
    o0 = (int)(m % GS) * 64;
    p0 = (int)(g & 63) * 64;
    b  = (int)(g >> 6);
}

// ---------------- K0a: split kv+q weights into bf16 hi/lo (one launch) ----------------
__global__ __launch_bounds__(256) void split2_kernel(const float* __restrict__ Wkv,
                                                     const float* __restrict__ Wq,
                                                     u16* __restrict__ KH, u16* __restrict__ KL,
                                                     u16* __restrict__ QH, u16* __restrict__ QL) {
    int i = blockIdx.x * 256 + threadIdx.x;
    if (i < 262144) {
        float v = Wkv[i]; u16 hb = f2h(v);
        KH[i] = hb; KL[i] = f2h(v - h2f(hb));
    } else {
        int j = i - 262144;
        float v = Wq[j]; u16 hb = f2h(v);
        QH[j] = hb; QL[j] = f2h(v - h2f(hb));
    }
}

// ---------------- K0b: split a weight, hi only ----------------
__global__ __launch_bounds__(256) void wsplit_hi_kernel(const float* __restrict__ W,
                                                        u16* __restrict__ WH) {
    int i = blockIdx.x * 256 + threadIdx.x;
    WH[i] = f2h(W[i]);
}

// ---------------- K1: channel LN -> transposed bf16 hi/lo [b][p][c] ----------------
__global__ __launch_bounds__(256) void ln_split_kernel(const float* __restrict__ x,
                                                       const float* __restrict__ g,
                                                       const float* __restrict__ bb,
                                                       u16* __restrict__ XH,
                                                       u16* __restrict__ XL) {
    int b = blockIdx.y;
    int p0 = blockIdx.x * 64;
    int tid = threadIdx.x;
    int px = tid & 63, cg = tid >> 6;
    __shared__ float red_s[4][64], red_q[4][64], meanv[64], rstdv[64];

    const float* xb = x + (size_t)b * CDIM * PP + p0 + px;
    float s = 0.f, sq = 0.f;
#pragma unroll 8
    for (int i = 0; i < 64; ++i) {
        float v = xb[(size_t)(cg * 64 + i) * PP];
        s += v; sq += v * v;
    }
    red_s[cg][px] = s; red_q[cg][px] = sq;
    __syncthreads();
    if (tid < 64) {
        float ts = red_s[0][tid] + red_s[1][tid] + red_s[2][tid] + red_s[3][tid];
        float tq = red_q[0][tid] + red_q[1][tid] + red_q[2][tid] + red_q[3][tid];
        float mean = ts * (1.f / CDIM);
        float var  = tq * (1.f / CDIM) - mean * mean;
        meanv[tid] = mean;
        rstdv[tid] = rsqrtf(var + 1e-5f);
    }
    __syncthreads();
    float mean = meanv[px], rstd = rstdv[px];
    size_t orow = ((size_t)b * PP + p0 + px) * CDIM;
    for (int c0 = cg * 64; c0 < cg * 64 + 64; c0 += 8) {
        short8 hv, lv;
#pragma unroll
        for (int j = 0; j < 8; ++j) {
            int c = c0 + j;
            float v = xb[(size_t)c * PP];
            float n = (v - mean) * rstd * g[c] + bb[c];
            u16 hb = f2h(n);
            hv[j] = (short)hb;
            lv[j] = (short)f2h(n - h2f(hb));
        }
        *(short8*)(XH + orow + c0) = hv;
        *(short8*)(XL + orow + c0) = lv;
    }
}

// ---------------- K2: MFMA conv1x1 GEMM, bf16x3 (K/Q) / hi-only (V) ----------------
// mode 0 (kv): K tiles (o<512) bf16x3 -> folded store + colscore_part;
//              V tiles (o>=512) hi-only -> folded store.
// mode 1 (q):  bf16x3, transposed store q_t[bh][p][d] + qprobe_part.
__global__ __launch_bounds__(256) void mfma_qkv_kernel(const u16* __restrict__ WH,
                                                       const u16* __restrict__ WL,
                                                       const u16* __restrict__ XH,
                                                       const u16* __restrict__ XL,
                                                       u16* __restrict__ dstA,
                                                       u16* __restrict__ dstB,
                                                       int Kdim, int norm_below, int mode,
                                                       float* __restrict__ part_out,
                                                       const float* __restrict__ q_probe) {
    __shared__ alignas(16) char sm[32768];   // AH|AL|BH|BL (8K each), later C[64][65] f32
    __shared__ float red[16][64];
    __shared__ float rinv[64];
    __shared__ float qp_s[64];
    char* AH = sm;
    char* AL = sm + 8192;
    char* BH = sm + 16384;
    char* BL = sm + 24576;
    float* C = (float*)sm;

    int o0, p0, b;
    remap(o0, p0, b);
    int tid = threadIdx.x;
    int l = tid & 63, w = tid >> 6;
    int wm = w >> 1, wn = w & 1;
    int lr = l & 15, lk = l >> 4;
    int r8 = l >> 3;
    int kswz = ((l & 7) * 16) ^ (r8 << 4);

    bool donorm = (o0 < norm_below);
    bool lite = (mode == 0) && !donorm;     // V tiles: hi-only path
    if (mode == 0 && donorm && tid < 64)
        qp_s[tid] = q_probe[(size_t)(b * NHEADS + (o0 >> 6)) * 64 + tid];

    f32x4 acc[2][2] = {};

    for (int k0 = 0; k0 < Kdim; k0 += 64) {
#pragma unroll
        for (int j = 0; j < 2; ++j) {
            int rb = w * 16 + j * 8;
            int row = rb + r8;
            size_t aoff = ((size_t)(o0 + row) * Kdim + k0) * 2 + kswz;
            size_t boff = (((size_t)b * PP + p0 + row) * Kdim + k0) * 2 + kswz;
            gload16((const char*)WH + aoff, AH + rb * 128);
            gload16((const char*)XH + boff, BH + rb * 128);
            if (!lite) {
                gload16((const char*)WL + aoff, AL + rb * 128);
                gload16((const char*)XL + boff, BL + rb * 128);
            }
        }
        __syncthreads();
#pragma unroll
        for (int kk = 0; kk < 2; ++kk) {
            int kb = kk * 64 + lk * 16;
            short8 ah[2], bh[2];
#pragma unroll
            for (int f = 0; f < 2; ++f) {
                ah[f] = *(short8*)(AH + sw(wm * 32 + f * 16 + lr, kb));
                bh[f] = *(short8*)(BH + sw(wn * 32 + f * 16 + lr, kb));
            }
            if (!lite) {
                short8 al[2], bl[2];
#pragma unroll
                for (int f = 0; f < 2; ++f) {
                    al[f] = *(short8*)(AL + sw(wm * 32 + f * 16 + lr, kb));
                    bl[f] = *(short8*)(BL + sw(wn * 32 + f * 16 + lr, kb));
                }
#pragma unroll
                for (int fm = 0; fm < 2; ++fm)
#pragma unroll
                    for (int fn = 0; fn < 2; ++fn) {
                        acc[fm][fn] = __builtin_amdgcn_mfma_f32_16x16x32_bf16(ah[fm], bh[fn], acc[fm][fn], 0, 0, 0);
                        acc[fm][fn] = __builtin_amdgcn_mfma_f32_16x16x32_bf16(ah[fm], bl[fn], acc[fm][fn], 0, 0, 0);
                        acc[fm][fn] = __builtin_amdgcn_mfma_f32_16x16x32_bf16(al[fm], bh[fn], acc[fm][fn], 0, 0, 0);
                    }
            } else {
#pragma unroll
                for (int fm = 0; fm < 2; ++fm)
#pragma unroll
                    for (int fn = 0; fn < 2; ++fn)
                        acc[fm][fn] = __builtin_amdgcn_mfma_f32_16x16x32_bf16(ah[fm], bh[fn], acc[fm][fn], 0, 0, 0);
            }
        }
        __syncthreads();
    }

    // ---- dump fp32 C tile to LDS (verified layout) ----
#pragma unroll
    for (int fm = 0; fm < 2; ++fm)
#pragma unroll
        for (int fn = 0; fn < 2; ++fn)
#pragma unroll
            for (int r = 0; r < 4; ++r)
                C[(wm * 32 + fm * 16 + lk * 4 + r) * 65 + wn * 32 + fn * 16 + lr] = acc[fm][fn][r];
    __syncthreads();

    int tx = tid & 15, ty = tid >> 4;
    float a2[4][4];
#pragma unroll
    for (int i = 0; i < 4; ++i)
#pragma unroll
        for (int j = 0; j < 4; ++j)
            a2[i][j] = C[(ty * 4 + i) * 65 + tx * 4 + j];

    // ---- l2norm (verified) ----
    if (donorm) {
#pragma unroll
        for (int j = 0; j < 4; ++j) {
            float sj = 0.f;
#pragma unroll
            for (int i = 0; i < 4; ++i) sj += a2[i][j] * a2[i][j];
            red[ty][tx * 4 + j] = sj;
        }
        __syncthreads();
        if (tid < 64) {
            float s = 0.f;
#pragma unroll
            for (int yy = 0; yy < 16; ++yy) s += red[yy][tid];
            rinv[tid] = 1.f / fmaxf(sqrtf(s), 1e-12f);
        }
        __syncthreads();
#pragma unroll
        for (int i = 0; i < 4; ++i)
#pragma unroll
            for (int j = 0; j < 4; ++j)
                a2[i][j] *= rinv[tx * 4 + j];
    }

    if (mode == 1) {
        // transposed normalized store: q_t[(bh*PP + p)*64 + d], from intact C tile
        int p_l = tid & 63, og = tid >> 6;
        float rv = rinv[p_l];
        u16* qrow = dstA + ((size_t)(b * NHEADS + (o0 >> 6)) * PP + p0 + p_l) * 64 + og * 16;
        short8 s0, s1;
#pragma unroll
        for (int i = 0; i < 8; ++i) s0[i] = (short)f2h(C[(og * 16 + i) * 65 + p_l] * rv);
#pragma unroll
        for (int i = 0; i < 8; ++i) s1[i] = (short)f2h(C[(og * 16 + 8 + i) * 65 + p_l] * rv);
        *(short8*)qrow = s0;
        *(short8*)(qrow + 8) = s1;
    } else {
        int oo = donorm ? o0 : (o0 - norm_below);
        u16* dest = donorm ? dstA : dstB;
#pragma unroll
        for (int i = 0; i < 4; ++i) {
            int oc = oo + ty * 4 + i;
            int bh = b * NHEADS + (oc >> 6);
            int d  = oc & 63;
            u16* drow = dest + ((size_t)bh * DHEAD + d) * PP + p0;
            short4v pk;
#pragma unroll
            for (int j = 0; j < 4; ++j) pk[j] = (short)f2h(a2[i][j]);
            *(short4v*)(drow + tx * 4) = pk;
        }
    }

    // ---- atomic-free score partials ----
    if (donorm) {
        int bh = b * NHEADS + (o0 >> 6);
        int h  = p0 >> 6;                       // one tile == one spatial row
        if (mode == 0) {
            float cj[4];
#pragma unroll
            for (int j = 0; j < 4; ++j) {
                float s = 0.f;
#pragma unroll
                for (int i = 0; i < 4; ++i) s += qp_s[ty * 4 + i] * fabsf(a2[i][j]);
                cj[j] = s;
            }
            __syncthreads();
#pragma unroll
            for (int j = 0; j < 4; ++j) red[ty][tx * 4 + j] = cj[j];
            __syncthreads();
            if (tid < 64) {
                float s = 0.f;
#pragma unroll
                for (int t = 0; t < 16; ++t) s += red[t][tid];
                part_out[((size_t)bh * 64 + h) * 64 + tid] = s;   // colscore_part
            }
        } else {
            float part[4];
#pragma unroll
            for (int i = 0; i < 4; ++i) {
                float s = 0.f;
#pragma unroll
                for (int j = 0; j < 4; ++j) s += a2[i][j];
                part[i] = s;
            }
            __syncthreads();
#pragma unroll
            for (int i = 0; i < 4; ++i) red[tx][ty * 4 + i] = part[i];
            __syncthreads();
            if (tid < 64) {
                float s = 0.f;
#pragma unroll
                for (int t = 0; t < 16; ++t) s += red[t][tid];
                part_out[((size_t)bh * 64 + h) * 64 + tid] = s;   // qprobe_part
            }
        }
    }
}

// ---------------- K3: q_probe[bh][d] = sum_h qprobe_part[bh][h][d] ----------------
__global__ __launch_bounds__(64) void qreduce_kernel(const float* __restrict__ part,
                                                     float* __restrict__ q_probe) {
    int bh = blockIdx.x, d = threadIdx.x;
    float s = 0.f;
    for (int h = 0; h < 64; ++h) s += part[((size_t)bh * 64 + h) * 64 + d];
    q_probe[(size_t)bh * 64 + d] = s;
}

// ---------------- K4: scores from colscore_part, top-8, gather ----------------
// k_sel[bh][j][d]; v_selt[bh][d][j] (transposed for PV B-operand)
__global__ __launch_bounds__(256) void select_gather_kernel(const float* __restrict__ colpart,
                                                            const u16* __restrict__ kn,
                                                            const u16* __restrict__ vs,
                                                            u16* __restrict__ k_sel,
                                                            u16* __restrict__ v_selt) {
    int bh = blockIdx.x;
    int tid = threadIdx.x;
    __shared__ float M[64][65];
    __shared__ int selh[8], selw[8];
    for (int i = tid; i < 4096; i += 256) M[i >> 6][i & 63] = colpart[(size_t)bh * 4096 + i];
    __syncthreads();
    if (tid < 128) {
        int isCol = tid >> 6;
        int x = tid & 63;
        float sv = 0.f;
        if (isCol) { for (int h = 0; h < 64; ++h) sv += M[h][x]; }
        else       { for (int w = 0; w < 64; ++w) sv += M[x][w]; }
        float v = sv;
        for (int it = 0; it < 8; ++it) {
            float bv = v; int bi = x;
#pragma unroll
            for (int off = 32; off; off >>= 1) {
                float ov = __shfl_xor(bv, off);
                int   oi = __shfl_xor(bi, off);
                if (ov > bv || (ov == bv && oi < bi)) { bv = ov; bi = oi; }
            }
            if (x == 0) { if (isCol) selw[it] = bi; else selh[it] = bi; }
            if (x == bi) v = -3.4e38f;
        }
    }
    __syncthreads();
    for (int idx = tid; idx < 4096; idx += 256) {
        int j = idx >> 6, d = idx & 63;
        int p = selh[j >> 3] * 64 + selw[j & 7];
        u16 kv = kn[((size_t)bh * 64 + d) * PP + p];
        u16 vv = vs[((size_t)bh * 64 + d) * PP + p];
        k_sel[(size_t)bh * 4096 + j * 64 + d]  = kv;
        v_selt[(size_t)bh * 4096 + d * 64 + j] = vv;
    }
}

// ---------------- K5: MFMA attention; writes transposed [b][p][inner] ----------------
__global__ __launch_bounds__(256) void attn_mfma_kernel(const u16* __restrict__ qt,
                                                        const u16* __restrict__ ksel,
                                                        const u16* __restrict__ vselt,
                                                        u16* __restrict__ attn_t) {
    __shared__ alignas(16) char AQ[8192];    // Q tile, then P tile
    __shared__ alignas(16) char BK[8192];    // K tile
    __shared__ alignas(16) char BV[8192];    // V^T tile
    __shared__ float SIM[64 * 68];
    int bh = blockIdx.y;
    int p0 = blockIdx.x * 64;
    int b = bh >> 3, h = bh & 7;
    int tid = threadIdx.x;
    int l = tid & 63, w = tid >> 6;
    int wm = w >> 1, wn = w & 1;
    int lr = l & 15, lk = l >> 4;
    int r8 = l >> 3;
    int kswz = ((l & 7) * 16) ^ (r8 << 4);

#pragma unroll
    for (int j = 0; j < 2; ++j) {
        int rb = w * 16 + j * 8;
        int row = rb + r8;
        gload16((const char*)qt + ((size_t)bh * PP + p0 + row) * 128 + kswz, AQ + rb * 128);
        gload16((const char*)ksel + ((size_t)bh * 64 + row) * 128 + kswz, BK + rb * 128);
        gload16((const char*)vselt + ((size_t)bh * 64 + row) * 128 + kswz, BV + rb * 128);
    }
    __syncthreads();

    // MFMA1: sim[p][j] = sum_d Q[p][d] K[j][d]
    f32x4 acc[2][2] = {};
#pragma unroll
    for (int kk = 0; kk < 2; ++kk) {
        int kb = kk * 64 + lk * 16;
        short8 av[2], bv[2];
#pragma unroll
        for (int f = 0; f < 2; ++f) {
            av[f] = *(short8*)(AQ + sw(wm * 32 + f * 16 + lr, kb));
            bv[f] = *(short8*)(BK + sw(wn * 32 + f * 16 + lr, kb));
        }
#pragma unroll
        for (int fm = 0; fm < 2; ++fm)
#pragma unroll
            for (int fn = 0; fn < 2; ++fn)
                acc[fm][fn] = __builtin_amdgcn_mfma_f32_16x16x32_bf16(av[fm], bv[fn], acc[fm][fn], 0, 0, 0);
    }
#pragma unroll
    for (int fm = 0; fm < 2; ++fm)
#pragma unroll
        for (int fn = 0; fn < 2; ++fn)
#pragma unroll
            for (int r = 0; r < 4; ++r)
                SIM[(wm * 32 + fm * 16 + lk * 4 + r) * 68 + wn * 32 + fn * 16 + lr] = acc[fm][fn][r];
    __syncthreads();

    // softmax over j (4 lanes per row p), P*(1/l) -> bf16 into AQ (swizzled)
    {
        int p = tid >> 2, qd = tid & 3;
        const float* srow = &SIM[p * 68 + qd * 16];
        float v[16];
#pragma unroll
        for (int jj = 0; jj < 16; ++jj) v[jj] = srow[jj];
        float m = v[0];
#pragma unroll
        for (int jj = 1; jj < 16; ++jj) m = fmaxf(m, v[jj]);
        m = fmaxf(m, __shfl_xor(m, 1));
        m = fmaxf(m, __shfl_xor(m, 2));
        float s = 0.f;
#pragma unroll
        for (int jj = 0; jj < 16; ++jj) { v[jj] = __expf(v[jj] - m); s += v[jj]; }
        s += __shfl_xor(s, 1);
        s += __shfl_xor(s, 2);
        float rl = 1.f / s;
        short8 h0, h1;
#pragma unroll
        for (int jj = 0; jj < 8; ++jj) {
            h0[jj] = (short)f2h(v[jj] * rl);
            h1[jj] = (short)f2h(v[8 + jj] * rl);
        }
        *(short8*)(AQ + sw(p, qd * 32)) = h0;
        *(short8*)(AQ + sw(p, qd * 32 + 16)) = h1;
    }
    __syncthreads();

    // MFMA2: out[p][d] = sum_j P[p][j] V^T[d][j]
    f32x4 acc2[2][2] = {};
#pragma unroll
    for (int kk = 0; kk < 2; ++kk) {
        int kb = kk * 64 + lk * 16;
        short8 av[2], bv[2];
#pragma unroll
        for (int f = 0; f < 2; ++f) {
            av[f] = *(short8*)(AQ + sw(wm * 32 + f * 16 + lr, kb));
            bv[f] = *(short8*)(BV + sw(wn * 32 + f * 16 + lr, kb));
        }
#pragma unroll
        for (int fm = 0; fm < 2; ++fm)
#pragma unroll
            for (int fn = 0; fn < 2; ++fn)
                acc2[fm][fn] = __builtin_amdgcn_mfma_f32_16x16x32_bf16(av[fm], bv[fn], acc2[fm][fn], 0, 0, 0);
    }
    u16* ob = attn_t + ((size_t)b * PP + p0) * INNER + h * 64;
#pragma unroll
    for (int fm = 0; fm < 2; ++fm)
#pragma unroll
        for (int fn = 0; fn < 2; ++fn)
#pragma unroll
            for (int r = 0; r < 4; ++r)
                ob[(size_t)(wm * 32 + fm * 16 + lk * 4 + r) * INNER + wn * 32 + fn * 16 + lr]
                    = f2h(acc2[fm][fn][r]);
}

// ---------------- K6: MFMA w_out GEMM, 2-phase double-buffered -> y fp32 ----------------
__global__ __launch_bounds__(256) void mfma_out_kernel(const u16* __restrict__ WHp,
                                                       const u16* __restrict__ Xt,
                                                       float* __restrict__ Y) {
    __shared__ alignas(16) char sm[32768];   // 2 bufs x (AH 8K | BH 8K)

    int o0, p0, b;
    remap(o0, p0, b);
    int tid = threadIdx.x;
    int l = tid & 63, w = tid >> 6;
    int wm = w >> 1, wn = w & 1;
    int lr = l & 15, lk = l >> 4;
    int r8 = l >> 3;
    int kswz = ((l & 7) * 16) ^ (r8 << 4);

    f32x4 acc[2][2] = {};

    auto STAGE = [&](int bufi, int k0) {
        char* base = sm + bufi * 16384;
#pragma unroll
        for (int j = 0; j < 2; ++j) {
            int rb = w * 16 + j * 8;
            int row = rb + r8;
            size_t aoff = ((size_t)(o0 + row) * INNER + k0) * 2 + kswz;
            size_t boff = (((size_t)b * PP + p0 + row) * INNER + k0) * 2 + kswz;
            gload16((const char*)WHp + aoff, base + rb * 128);
            gload16((const char*)Xt + boff, base + 8192 + rb * 128);
        }
    };

    STAGE(0, 0);
    __syncthreads();
    int cur = 0;
    for (int t = 0; t < 8; ++t) {
        if (t < 7) STAGE(cur ^ 1, (t + 1) * 64);     // prefetch next (overlaps MFMA)
        char* AH = sm + cur * 16384;
        char* BH = AH + 8192;
#pragma unroll
        for (int kk = 0; kk < 2; ++kk) {
            int kb = kk * 64 + lk * 16;
            short8 ah[2], bh[2];
#pragma unroll
            for (int f = 0; f < 2; ++f) {
                ah[f] = *(short8*)(AH + sw(wm * 32 + f * 16 + lr, kb));
                bh[f] = *(short8*)(BH + sw(wn * 32 + f * 16 + lr, kb));
            }
#pragma unroll
            for (int fm = 0; fm < 2; ++fm)
#pragma unroll
                for (int fn = 0; fn < 2; ++fn)
                    acc[fm][fn] = __builtin_amdgcn_mfma_f32_16x16x32_bf16(ah[fm], bh[fn], acc[fm][fn], 0, 0, 0);
        }
        __syncthreads();   // drains prefetch loads; next iter reads them
        cur ^= 1;
    }
#pragma unroll
    for (int fm = 0; fm < 2; ++fm)
#pragma unroll
        for (int fn = 0; fn < 2; ++fn)
#pragma unroll
            for (int r = 0; r < 4; ++r)
                Y[((size_t)b * CDIM + o0 + wm * 32 + fm * 16 + lk * 4 + r) * PP
                  + p0 + wn * 32 + fn * 16 + lr] = acc[fm][fn][r];
}

// ---------------- K7: final LN + gamma*out + residual ----------------
__global__ __launch_bounds__(256) void final_ln_kernel(const float* __restrict__ y,
                                                       const float* __restrict__ g,
                                                       const float* __restrict__ bb,
                                                       const float* __restrict__ gamma,
                                                       const float* __restrict__ resid,
                                                       float* __restrict__ out) {
    int b = blockIdx.y;
    int p = blockIdx.x * 256 + threadIdx.x;
    const float* yb = y + (size_t)b * CDIM * PP + p;
    float s = 0.f, sq = 0.f;
    for (int c = 0; c < CDIM; ++c) {
        float v = yb[(size_t)c * PP];
        s += v; sq += v * v;
    }
    float mean = s * (1.f / CDIM);
    float var  = sq * (1.f / CDIM) - mean * mean;
    float rstd = rsqrtf(var + 1e-5f);
    float gm = gamma[0];
    const float* rb = resid + (size_t)b * CDIM * PP + p;
    float* ob = out + (size_t)b * CDIM * PP + p;
    for (int c = 0; c < CDIM; ++c) {
        float v = yb[(size_t)c * PP];
        float xn = (v - mean) * rstd * g[c] + bb[c];
        ob[(size_t)c * PP] = gm * xn + rb[(size_t)c * PP];
    }
}

extern "C" void kernel_launch(void* const* d_in, const int* in_sizes, int n_in,
                              void* d_out, int out_size, void* d_ws, size_t ws_size,
                              hipStream_t stream) {
    const float* query_source = (const float*)d_in[0];
    const float* context      = (const float*)d_in[1];
    const float* cn_g = (const float*)d_in[2];
    const float* cn_b = (const float*)d_in[3];
    const float* qn_g = (const float*)d_in[4];
    const float* qn_b = (const float*)d_in[5];
    const float* on_g = (const float*)d_in[6];
    const float* on_b = (const float*)d_in[7];
    const float* w_kv = (const float*)d_in[8];
    const float* w_q  = (const float*)d_in[9];
    const float* w_out= (const float*)d_in[10];
    const float* gamma= (const float*)d_in[11];
    float* out = (float*)d_out;

    char* ws = (char*)d_ws;
    // [0,32M): XHt(16M)+XLt(16M) (qs phase, then ctx phase); later attn_t (32M)
    u16*  XHt    = (u16*)(ws + 0);
    u16*  XLt    = (u16*)(ws + 16777216);
    u16*  attn_t = (u16*)(ws + 0);
    // [32M,64M): k_n bf16; later y fp32
    u16*   k_n  = (u16*)(ws + 33554432);
    float* y    = (float*)(ws + 33554432);
    u16*   v_s  = (u16*)(ws + 67108864);       // [64M,96M)
    u16*   q_t  = (u16*)(ws + 100663296);      // [96M,128M) transposed q [bh][p][d]
    // [128M..): small buffers with disjoint lifetimes
    u16*  WqH   = (u16*)(ws + 134217728);      // 512K (dead after q GEMM)
    u16*  WqL   = (u16*)(ws + 134742016);      // 512K
    u16*  k_sel = (u16*)(ws + 134217728);      // aliases WqH
    u16*  v_selt= (u16*)(ws + 134742016);      // aliases WqL
    u16*  WkvH  = (u16*)(ws + 135266304);      // 512K (dead after kv GEMM)
    u16*  WkvL  = (u16*)(ws + 135790592);      // 512K
    u16*  WoutH = (u16*)(ws + 135266304);      // 256K, aliases WkvH
    float* qprobe_part   = (float*)(ws + 136314880); // 1M (dead after qreduce)
    float* colscore_part = (float*)(ws + 136314880); // 1M, aliases qprobe_part
    float* q_probe       = (float*)(ws + 137363456); // 16K

    dim3 blk(256);
    // ---- weight splits (kv+q fused into one launch) ----
    split2_kernel<<<dim3(1536), blk, 0, stream>>>(w_kv, w_q, WkvH, WkvL, WqH, WqL);
    // ---- q pipeline (produces q_probe before kv GEMM) ----
    ln_split_kernel<<<dim3(64, BB), blk, 0, stream>>>(query_source, qn_g, qn_b, XHt, XLt);
    mfma_qkv_kernel<<<dim3(8, 64, BB), blk, 0, stream>>>(WqH, WqL, XHt, XLt, q_t, nullptr,
                                                         CDIM, 512, 1, qprobe_part, nullptr);
    qreduce_kernel<<<dim3(64), dim3(64), 0, stream>>>(qprobe_part, q_probe);
    // ---- kv pipeline ----
    ln_split_kernel<<<dim3(64, BB), blk, 0, stream>>>(context, cn_g, cn_b, XHt, XLt);
    mfma_qkv_kernel<<<dim3(16, 64, BB), blk, 0, stream>>>(WkvH, WkvL, XHt, XLt, k_n, v_s,
                                                          CDIM, 512, 0, colscore_part, q_probe);
    // ---- select / attention / output ----
    select_gather_kernel<<<dim3(64), blk, 0, stream>>>(colscore_part, k_n, v_s, k_sel, v_selt);
    wsplit_hi_kernel<<<dim3(512), blk, 0, stream>>>(w_out, WoutH);
    attn_mfma_kernel<<<dim3(64, NBH), blk, 0, stream>>>(q_t, k_sel, v_selt, attn_t);
    mfma_out_kernel<<<dim3(4, 64, BB), blk, 0, stream>>>(WoutH, attn_t, y);
    final_ln_kernel<<<dim3(16, BB), blk, 0, stream>>>(y, on_g, on_b, gamma, query_source, out);
}

// Round 8
// 352.545 us; speedup vs baseline: 3.6246x; 1.0866x over previous
//
#include <hip/hip_runtime.h>
#include <hip/hip_bf16.h>

#define BB 8
#define CDIM 256
#define PP 4096
#define NHEADS 8
#define DHEAD 64
#define INNER 512
#define NBH 64

using bf16 = __hip_bfloat16;
typedef short short8 __attribute__((ext_vector_type(8)));
typedef short short4v __attribute__((ext_vector_type(4)));
typedef float f32x4 __attribute__((ext_vector_type(4)));
typedef unsigned short u16;

__device__ __forceinline__ float b2f(bf16 x) { return __bfloat162float(x); }

__device__ __forceinline__ u16 f2h(float x) {
    union { float f; unsigned u; } c; c.f = x;
    unsigned r = c.u + 0x7FFF + ((c.u >> 16) & 1);
    return (u16)(r >> 16);
}
__device__ __forceinline__ float h2f(u16 h) {
    union { float f; unsigned u; } c; c.u = ((unsigned)h) << 16;
    return c.f;
}

// XOR-swizzled byte offset inside a [64 rows][128 B] LDS tile
__device__ __forceinline__ int sw(int row, int kb) {
    return row * 128 + (kb ^ ((row & 7) << 4));
}

// async global->LDS, 16B per lane; lds base wave-uniform, HW adds lane*16
__device__ __forceinline__ void gload16(const void* g, void* lds) {
    __builtin_amdgcn_global_load_lds((const __attribute__((address_space(1))) void*)g,
                                     (__attribute__((address_space(3))) void*)lds, 16, 0, 0);
}

// XCD-aware remap (verified round 4): o-tiles sharing an X chunk land on one XCD.
__device__ __forceinline__ void remap_i(int& i, int& p0, int& b) {
    unsigned GS = gridDim.x;
    unsigned h = (blockIdx.z * gridDim.y + blockIdx.y) * GS + blockIdx.x;
    unsigned xc = h & 7, m = h >> 3;
    unsigned g = (m / GS) * 8 + xc;
    i  = (int)(m % GS);
    p0 = (int)(g & 63) * 64;
    b  = (int)(g >> 6);
}

// ---------------- K0a: split kv+q weights into bf16 hi/lo ----------------
__global__ __launch_bounds__(256) void split2_kernel(const float* __restrict__ Wkv,
                                                     const float* __restrict__ Wq,
                                                     u16* __restrict__ KH, u16* __restrict__ KL,
                                                     u16* __restrict__ QH, u16* __restrict__ QL) {
    int i = blockIdx.x * 256 + threadIdx.x;
    if (i < 262144) {
        float v = Wkv[i]; u16 hb = f2h(v);
        KH[i] = hb; KL[i] = f2h(v - h2f(hb));
    } else {
        int j = i - 262144;
        float v = Wq[j]; u16 hb = f2h(v);
        QH[j] = hb; QL[j] = f2h(v - h2f(hb));
    }
}

// ---------------- K0b: split a weight, hi only ----------------
__global__ __launch_bounds__(256) void wsplit_hi_kernel(const float* __restrict__ W,
                                                        u16* __restrict__ WH) {
    int i = blockIdx.x * 256 + threadIdx.x;
    WH[i] = f2h(W[i]);
}

// ---------------- K1: channel LN -> transposed bf16 hi/lo [b][p][c], single global read ----
__global__ __launch_bounds__(256) void ln_split_kernel(const float* __restrict__ x,
                                                       const float* __restrict__ g,
                                                       const float* __restrict__ bb,
                                                       u16* __restrict__ XH,
                                                       u16* __restrict__ XL) {
    __shared__ alignas(16) float xs[256][64];   // 64 KB, [c][p]
    __shared__ float red_s[4][64], red_q[4][64], meanv[64], rstdv[64];
    int b = blockIdx.y;
    int p0 = blockIdx.x * 64;
    int tid = threadIdx.x;
    int w = tid >> 6, l = tid & 63;

    // stage 64 KB: issue ii covers 4 c-rows; lane l -> row l>>4, float col (l&15)*4
#pragma unroll
    for (int ii = 0; ii < 16; ++ii) {
        int iss = w * 16 + ii;
        int c = iss * 4 + (l >> 4);
        gload16(x + ((size_t)b * CDIM + c) * PP + p0 + (l & 15) * 4,
                (char*)xs + iss * 1024);
    }
    __syncthreads();

    int px = l, cg = w;
    float s = 0.f, sq = 0.f;
#pragma unroll 8
    for (int i = 0; i < 64; ++i) {
        float v = xs[cg * 64 + i][px];
        s += v; sq += v * v;
    }
    red_s[cg][px] = s; red_q[cg][px] = sq;
    __syncthreads();
    if (tid < 64) {
        float ts = red_s[0][tid] + red_s[1][tid] + red_s[2][tid] + red_s[3][tid];
        float tq = red_q[0][tid] + red_q[1][tid] + red_q[2][tid] + red_q[3][tid];
        float mean = ts * (1.f / CDIM);
        float var  = tq * (1.f / CDIM) - mean * mean;
        meanv[tid] = mean;
        rstdv[tid] = rsqrtf(var + 1e-5f);
    }
    __syncthreads();
    float mean = meanv[px], rstd = rstdv[px];
    size_t orow = ((size_t)b * PP + p0 + px) * CDIM;
    for (int c0 = cg * 64; c0 < cg * 64 + 64; c0 += 8) {
        short8 hv, lv;
#pragma unroll
        for (int j = 0; j < 8; ++j) {
            int c = c0 + j;
            float v = xs[c][px];
            float n = (v - mean) * rstd * g[c] + bb[c];
            u16 hb = f2h(n);
            hv[j] = (short)hb;
            lv[j] = (short)f2h(n - h2f(hb));
        }
        *(short8*)(XH + orow + c0) = hv;
        *(short8*)(XL + orow + c0) = lv;
    }
}

// ---------------- K2: FUSED MFMA conv1x1 GEMM (two o-tiles share the X staging) ------
// mode 0 (kv): tile A = K head i (bf16x3, l2norm, folded store, colscore),
//              tile B = V head i (hi-only, folded store). o0A=i*64, o0B=512+i*64.
// mode 1 (q):  tiles A,B = q heads i, i+4 (bf16x3, l2norm, transposed store, qprobe).
__global__ __launch_bounds__(256) void mfma_fused_kernel(const u16* __restrict__ WH,
                                                         const u16* __restrict__ WL,
                                                         const u16* __restrict__ XH,
                                                         const u16* __restrict__ XL,
                                                         u16* __restrict__ dstA,
                                                         u16* __restrict__ dstB,
                                                         int mode,
                                                         float* __restrict__ part_out,
                                                         const float* __restrict__ q_probe) {
    __shared__ alignas(16) char sm[49152];   // XH|XL|WaH|WaL|WbH|WbL tiles (8K each)
    char* SXH = sm;
    char* SXL = sm + 8192;
    char* SAH = sm + 16384;
    char* SAL = sm + 24576;
    char* SBH = sm + 32768;
    char* SBL = sm + 40960;
    // epilogue views alias dead staging space
    float* C    = (float*)sm;                 // [64][65] f32 = 16640 B
    float* red  = (float*)(sm + 16640);       // [16][64]     = 4096 B
    float* rinv = (float*)(sm + 20736);       // 64 f32
    float* qp_s = (float*)(sm + 20992);       // 64 f32

    int i, p0, b;
    remap_i(i, p0, b);
    int o0A = i * 64;
    int o0B = (mode == 0) ? 512 + i * 64 : 256 + i * 64;
    int tid = threadIdx.x;
    int l = tid & 63, w = tid >> 6;
    int wm = w >> 1, wn = w & 1;
    int lr = l & 15, lk = l >> 4;
    int r8 = l >> 3;
    int kswz = ((l & 7) * 16) ^ (r8 << 4);

    f32x4 accA[2][2] = {};
    f32x4 accB[2][2] = {};

    for (int k0 = 0; k0 < CDIM; k0 += 64) {
#pragma unroll
        for (int j = 0; j < 2; ++j) {
            int rb = w * 16 + j * 8;
            int row = rb + r8;
            size_t boff  = (((size_t)b * PP + p0 + row) * CDIM + k0) * 2 + kswz;
            size_t aoffA = ((size_t)(o0A + row) * CDIM + k0) * 2 + kswz;
            size_t aoffB = ((size_t)(o0B + row) * CDIM + k0) * 2 + kswz;
            gload16((const char*)XH + boff,  SXH + rb * 128);
            gload16((const char*)XL + boff,  SXL + rb * 128);
            gload16((const char*)WH + aoffA, SAH + rb * 128);
            gload16((const char*)WL + aoffA, SAL + rb * 128);
            gload16((const char*)WH + aoffB, SBH + rb * 128);
            if (mode == 1) gload16((const char*)WL + aoffB, SBL + rb * 128);
        }
        __syncthreads();
#pragma unroll
        for (int kk = 0; kk < 2; ++kk) {
            int kb = kk * 64 + lk * 16;
            short8 xh_[2], xl_[2], ahA[2], alA[2], ahB[2], alB[2];
#pragma unroll
            for (int f = 0; f < 2; ++f) {
                int rx = wn * 32 + f * 16 + lr;
                int rw = wm * 32 + f * 16 + lr;
                xh_[f] = *(short8*)(SXH + sw(rx, kb));
                xl_[f] = *(short8*)(SXL + sw(rx, kb));
                ahA[f] = *(short8*)(SAH + sw(rw, kb));
                alA[f] = *(short8*)(SAL + sw(rw, kb));
                ahB[f] = *(short8*)(SBH + sw(rw, kb));
                alB[f] = (mode == 1) ? *(short8*)(SBL + sw(rw, kb)) : ahB[f];
            }
#pragma unroll
            for (int fm = 0; fm < 2; ++fm)
#pragma unroll
                for (int fn = 0; fn < 2; ++fn) {
                    accA[fm][fn] = __builtin_amdgcn_mfma_f32_16x16x32_bf16(ahA[fm], xh_[fn], accA[fm][fn], 0, 0, 0);
                    accA[fm][fn] = __builtin_amdgcn_mfma_f32_16x16x32_bf16(ahA[fm], xl_[fn], accA[fm][fn], 0, 0, 0);
                    accA[fm][fn] = __builtin_amdgcn_mfma_f32_16x16x32_bf16(alA[fm], xh_[fn], accA[fm][fn], 0, 0, 0);
                    accB[fm][fn] = __builtin_amdgcn_mfma_f32_16x16x32_bf16(ahB[fm], xh_[fn], accB[fm][fn], 0, 0, 0);
                    if (mode == 1) {
                        accB[fm][fn] = __builtin_amdgcn_mfma_f32_16x16x32_bf16(ahB[fm], xl_[fn], accB[fm][fn], 0, 0, 0);
                        accB[fm][fn] = __builtin_amdgcn_mfma_f32_16x16x32_bf16(alB[fm], xh_[fn], accB[fm][fn], 0, 0, 0);
                    }
                }
        }
        __syncthreads();
    }

    int tx = tid & 15, ty = tid >> 4;
    int h = p0 >> 6;                              // spatial row of this tile
    if (mode == 0 && tid < 64)
        qp_s[tid] = q_probe[(size_t)(b * NHEADS + i) * 64 + tid];

    // ================= TILE A (always l2norm) =================
#pragma unroll
    for (int fm = 0; fm < 2; ++fm)
#pragma unroll
        for (int fn = 0; fn < 2; ++fn)
#pragma unroll
            for (int r = 0; r < 4; ++r)
                C[(wm * 32 + fm * 16 + lk * 4 + r) * 65 + wn * 32 + fn * 16 + lr] = accA[fm][fn][r];
    __syncthreads();

    float a2[4][4];
#pragma unroll
    for (int ii = 0; ii < 4; ++ii)
#pragma unroll
        for (int j = 0; j < 4; ++j)
            a2[ii][j] = C[(ty * 4 + ii) * 65 + tx * 4 + j];

#pragma unroll
    for (int j = 0; j < 4; ++j) {
        float sj = 0.f;
#pragma unroll
        for (int ii = 0; ii < 4; ++ii) sj += a2[ii][j] * a2[ii][j];
        red[ty * 64 + tx * 4 + j] = sj;
    }
    __syncthreads();
    if (tid < 64) {
        float s = 0.f;
#pragma unroll
        for (int yy = 0; yy < 16; ++yy) s += red[yy * 64 + tid];
        rinv[tid] = 1.f / fmaxf(sqrtf(s), 1e-12f);
    }
    __syncthreads();
#pragma unroll
    for (int ii = 0; ii < 4; ++ii)
#pragma unroll
        for (int j = 0; j < 4; ++j)
            a2[ii][j] *= rinv[tx * 4 + j];

    int bhA = b * NHEADS + (o0A >> 6);
    if (mode == 0) {
        // folded packed K store
#pragma unroll
        for (int ii = 0; ii < 4; ++ii) {
            int oc = o0A + ty * 4 + ii;
            int d  = oc & 63;
            u16* drow = dstA + ((size_t)(b * NHEADS + (oc >> 6)) * DHEAD + d) * PP + p0;
            short4v pk;
#pragma unroll
            for (int j = 0; j < 4; ++j) pk[j] = (short)f2h(a2[ii][j]);
            *(short4v*)(drow + tx * 4) = pk;
        }
        // colscore partial
        float cj[4];
#pragma unroll
        for (int j = 0; j < 4; ++j) {
            float s = 0.f;
#pragma unroll
            for (int ii = 0; ii < 4; ++ii) s += qp_s[ty * 4 + ii] * fabsf(a2[ii][j]);
            cj[j] = s;
        }
        __syncthreads();
#pragma unroll
        for (int j = 0; j < 4; ++j) red[ty * 64 + tx * 4 + j] = cj[j];
        __syncthreads();
        if (tid < 64) {
            float s = 0.f;
#pragma unroll
            for (int t = 0; t < 16; ++t) s += red[t * 64 + tid];
            part_out[((size_t)bhA * 64 + h) * 64 + tid] = s;
        }
    } else {
        // transposed q store from intact C * rinv
        int p_l = tid & 63, og = tid >> 6;
        float rv = rinv[p_l];
        u16* qrow = dstA + ((size_t)bhA * PP + p0 + p_l) * 64 + og * 16;
        short8 s0, s1;
#pragma unroll
        for (int ii = 0; ii < 8; ++ii) s0[ii] = (short)f2h(C[(og * 16 + ii) * 65 + p_l] * rv);
#pragma unroll
        for (int ii = 0; ii < 8; ++ii) s1[ii] = (short)f2h(C[(og * 16 + 8 + ii) * 65 + p_l] * rv);
        *(short8*)qrow = s0;
        *(short8*)(qrow + 8) = s1;
        // qprobe partial
        float part[4];
#pragma unroll
        for (int ii = 0; ii < 4; ++ii) {
            float s = 0.f;
#pragma unroll
            for (int j = 0; j < 4; ++j) s += a2[ii][j];
            part[ii] = s;
        }
        __syncthreads();
#pragma unroll
        for (int ii = 0; ii < 4; ++ii) red[tx * 64 + ty * 4 + ii] = part[ii];
        __syncthreads();
        if (tid < 64) {
            float s = 0.f;
#pragma unroll
            for (int t = 0; t < 16; ++t) s += red[t * 64 + tid];
            part_out[((size_t)bhA * 64 + h) * 64 + tid] = s;
        }
    }
    __syncthreads();   // guard C/red/rinv reuse by tile B

    // ================= TILE B =================
#pragma unroll
    for (int fm = 0; fm < 2; ++fm)
#pragma unroll
        for (int fn = 0; fn < 2; ++fn)
#pragma unroll
            for (int r = 0; r < 4; ++r)
                C[(wm * 32 + fm * 16 + lk * 4 + r) * 65 + wn * 32 + fn * 16 + lr] = accB[fm][fn][r];
    __syncthreads();
#pragma unroll
    for (int ii = 0; ii < 4; ++ii)
#pragma unroll
        for (int j = 0; j < 4; ++j)
            a2[ii][j] = C[(ty * 4 + ii) * 65 + tx * 4 + j];

    if (mode == 0) {
        // V: folded packed store, no norm
#pragma unroll
        for (int ii = 0; ii < 4; ++ii) {
            int oc = (o0B - 512) + ty * 4 + ii;
            int d  = oc & 63;
            u16* drow = dstB + ((size_t)(b * NHEADS + (oc >> 6)) * DHEAD + d) * PP + p0;
            short4v pk;
#pragma unroll
            for (int j = 0; j < 4; ++j) pk[j] = (short)f2h(a2[ii][j]);
            *(short4v*)(drow + tx * 4) = pk;
        }
    } else {
        // second q head: full norm + transposed store + qprobe
#pragma unroll
        for (int j = 0; j < 4; ++j) {
            float sj = 0.f;
#pragma unroll
            for (int ii = 0; ii < 4; ++ii) sj += a2[ii][j] * a2[ii][j];
            red[ty * 64 + tx * 4 + j] = sj;
        }
        __syncthreads();
        if (tid < 64) {
            float s = 0.f;
#pragma unroll
            for (int yy = 0; yy < 16; ++yy) s += red[yy * 64 + tid];
            rinv[tid] = 1.f / fmaxf(sqrtf(s), 1e-12f);
        }
        __syncthreads();
#pragma unroll
        for (int ii = 0; ii < 4; ++ii)
#pragma unroll
            for (int j = 0; j < 4; ++j)
                a2[ii][j] *= rinv[tx * 4 + j];

        int bhB = b * NHEADS + (o0B >> 6);
        int p_l = tid & 63, og = tid >> 6;
        float rv = rinv[p_l];
        u16* qrow = dstA + ((size_t)bhB * PP + p0 + p_l) * 64 + og * 16;
        short8 s0, s1;
#pragma unroll
        for (int ii = 0; ii < 8; ++ii) s0[ii] = (short)f2h(C[(og * 16 + ii) * 65 + p_l] * rv);
#pragma unroll
        for (int ii = 0; ii < 8; ++ii) s1[ii] = (short)f2h(C[(og * 16 + 8 + ii) * 65 + p_l] * rv);
        *(short8*)qrow = s0;
        *(short8*)(qrow + 8) = s1;
        float part[4];
#pragma unroll
        for (int ii = 0; ii < 4; ++ii) {
            float s = 0.f;
#pragma unroll
            for (int j = 0; j < 4; ++j) s += a2[ii][j];
            part[ii] = s;
        }
        __syncthreads();
#pragma unroll
        for (int ii = 0; ii < 4; ++ii) red[tx * 64 + ty * 4 + ii] = part[ii];
        __syncthreads();
        if (tid < 64) {
            float s = 0.f;
#pragma unroll
            for (int t = 0; t < 16; ++t) s += red[t * 64 + tid];
            part_out[((size_t)bhB * 64 + h) * 64 + tid] = s;
        }
    }
}

// ---------------- K3: q_probe[bh][d] = sum_h qprobe_part[bh][h][d] ----------------
__global__ __launch_bounds__(64) void qreduce_kernel(const float* __restrict__ part,
                                                     float* __restrict__ q_probe) {
    int bh = blockIdx.x, d = threadIdx.x;
    float s = 0.f;
    for (int h = 0; h < 64; ++h) s += part[((size_t)bh * 64 + h) * 64 + d];
    q_probe[(size_t)bh * 64 + d] = s;
}

// ---------------- K4: scores from colscore_part, top-8, gather ----------------
__global__ __launch_bounds__(256) void select_gather_kernel(const float* __restrict__ colpart,
                                                            const u16* __restrict__ kn,
                                                            const u16* __restrict__ vs,
                                                            u16* __restrict__ k_sel,
                                                            u16* __restrict__ v_selt) {
    int bh = blockIdx.x;
    int tid = threadIdx.x;
    __shared__ float M[64][65];
    __shared__ int selh[8], selw[8];
    for (int i = tid; i < 4096; i += 256) M[i >> 6][i & 63] = colpart[(size_t)bh * 4096 + i];
    __syncthreads();
    if (tid < 128) {
        int isCol = tid >> 6;
        int x = tid & 63;
        float sv = 0.f;
        if (isCol) { for (int h = 0; h < 64; ++h) sv += M[h][x]; }
        else       { for (int w = 0; w < 64; ++w) sv += M[x][w]; }
        float v = sv;
        for (int it = 0; it < 8; ++it) {
            float bv = v; int bi = x;
#pragma unroll
            for (int off = 32; off; off >>= 1) {
                float ov = __shfl_xor(bv, off);
                int   oi = __shfl_xor(bi, off);
                if (ov > bv || (ov == bv && oi < bi)) { bv = ov; bi = oi; }
            }
            if (x == 0) { if (isCol) selw[it] = bi; else selh[it] = bi; }
            if (x == bi) v = -3.4e38f;
        }
    }
    __syncthreads();
    for (int idx = tid; idx < 4096; idx += 256) {
        int j = idx >> 6, d = idx & 63;
        int p = selh[j >> 3] * 64 + selw[j & 7];
        u16 kv = kn[((size_t)bh * 64 + d) * PP + p];
        u16 vv = vs[((size_t)bh * 64 + d) * PP + p];
        k_sel[(size_t)bh * 4096 + j * 64 + d]  = kv;
        v_selt[(size_t)bh * 4096 + d * 64 + j] = vv;
    }
}

// ---------------- K5: MFMA attention; writes transposed [b][p][inner] ----------------
__global__ __launch_bounds__(256) void attn_mfma_kernel(const u16* __restrict__ qt,
                                                        const u16* __restrict__ ksel,
                                                        const u16* __restrict__ vselt,
                                                        u16* __restrict__ attn_t) {
    __shared__ alignas(16) char AQ[8192];    // Q tile, then P tile
    __shared__ alignas(16) char BK[8192];    // K tile
    __shared__ alignas(16) char BV[8192];    // V^T tile
    __shared__ float SIM[64 * 68];
    int bh = blockIdx.y;
    int p0 = blockIdx.x * 64;
    int b = bh >> 3, h = bh & 7;
    int tid = threadIdx.x;
    int l = tid & 63, w = tid >> 6;
    int wm = w >> 1, wn = w & 1;
    int lr = l & 15, lk = l >> 4;
    int r8 = l >> 3;
    int kswz = ((l & 7) * 16) ^ (r8 << 4);

#pragma unroll
    for (int j = 0; j < 2; ++j) {
        int rb = w * 16 + j * 8;
        int row = rb + r8;
        gload16((const char*)qt + ((size_t)bh * PP + p0 + row) * 128 + kswz, AQ + rb * 128);
        gload16((const char*)ksel + ((size_t)bh * 64 + row) * 128 + kswz, BK + rb * 128);
        gload16((const char*)vselt + ((size_t)bh * 64 + row) * 128 + kswz, BV + rb * 128);
    }
    __syncthreads();

    f32x4 acc[2][2] = {};
#pragma unroll
    for (int kk = 0; kk < 2; ++kk) {
        int kb = kk * 64 + lk * 16;
        short8 av[2], bv[2];
#pragma unroll
        for (int f = 0; f < 2; ++f) {
            av[f] = *(short8*)(AQ + sw(wm * 32 + f * 16 + lr, kb));
            bv[f] = *(short8*)(BK + sw(wn * 32 + f * 16 + lr, kb));
        }
#pragma unroll
        for (int fm = 0; fm < 2; ++fm)
#pragma unroll
            for (int fn = 0; fn < 2; ++fn)
                acc[fm][fn] = __builtin_amdgcn_mfma_f32_16x16x32_bf16(av[fm], bv[fn], acc[fm][fn], 0, 0, 0);
    }
#pragma unroll
    for (int fm = 0; fm < 2; ++fm)
#pragma unroll
        for (int fn = 0; fn < 2; ++fn)
#pragma unroll
            for (int r = 0; r < 4; ++r)
                SIM[(wm * 32 + fm * 16 + lk * 4 + r) * 68 + wn * 32 + fn * 16 + lr] = acc[fm][fn][r];
    __syncthreads();

    {
        int p = tid >> 2, qd = tid & 3;
        const float* srow = &SIM[p * 68 + qd * 16];
        float v[16];
#pragma unroll
        for (int jj = 0; jj < 16; ++jj) v[jj] = srow[jj];
        float m = v[0];
#pragma unroll
        for (int jj = 1; jj < 16; ++jj) m = fmaxf(m, v[jj]);
        m = fmaxf(m, __shfl_xor(m, 1));
        m = fmaxf(m, __shfl_xor(m, 2));
        float s = 0.f;
#pragma unroll
        for (int jj = 0; jj < 16; ++jj) { v[jj] = __expf(v[jj] - m); s += v[jj]; }
        s += __shfl_xor(s, 1);
        s += __shfl_xor(s, 2);
        float rl = 1.f / s;
        short8 h0, h1;
#pragma unroll
        for (int jj = 0; jj < 8; ++jj) {
            h0[jj] = (short)f2h(v[jj] * rl);
            h1[jj] = (short)f2h(v[8 + jj] * rl);
        }
        *(short8*)(AQ + sw(p, qd * 32)) = h0;
        *(short8*)(AQ + sw(p, qd * 32 + 16)) = h1;
    }
    __syncthreads();

    f32x4 acc2[2][2] = {};
#pragma unroll
    for (int kk = 0; kk < 2; ++kk) {
        int kb = kk * 64 + lk * 16;
        short8 av[2], bv[2];
#pragma unroll
        for (int f = 0; f < 2; ++f) {
            av[f] = *(short8*)(AQ + sw(wm * 32 + f * 16 + lr, kb));
            bv[f] = *(short8*)(BV + sw(wn * 32 + f * 16 + lr, kb));
        }
#pragma unroll
        for (int fm = 0; fm < 2; ++fm)
#pragma unroll
            for (int fn = 0; fn < 2; ++fn)
                acc2[fm][fn] = __builtin_amdgcn_mfma_f32_16x16x32_bf16(av[fm], bv[fn], acc2[fm][fn], 0, 0, 0);
    }
    u16* ob = attn_t + ((size_t)b * PP + p0) * INNER + h * 64;
#pragma unroll
    for (int fm = 0; fm < 2; ++fm)
#pragma unroll
        for (int fn = 0; fn < 2; ++fn)
#pragma unroll
            for (int r = 0; r < 4; ++r)
                ob[(size_t)(wm * 32 + fm * 16 + lk * 4 + r) * INNER + wn * 32 + fn * 16 + lr]
                    = f2h(acc2[fm][fn][r]);
}

// ---------------- K6: MFMA w_out GEMM, 2-phase dbuf -> y bf16 ----------------
__global__ __launch_bounds__(256) void mfma_out_kernel(const u16* __restrict__ WHp,
                                                       const u16* __restrict__ Xt,
                                                       u16* __restrict__ Y) {
    __shared__ alignas(16) char sm[32768];   // 2 bufs x (AH 8K | BH 8K)

    int i, p0, b;
    remap_i(i, p0, b);
    int o0 = i * 64;
    int tid = threadIdx.x;
    int l = tid & 63, w = tid >> 6;
    int wm = w >> 1, wn = w & 1;
    int lr = l & 15, lk = l >> 4;
    int r8 = l >> 3;
    int kswz = ((l & 7) * 16) ^ (r8 << 4);

    f32x4 acc[2][2] = {};

    auto STAGE = [&](int bufi, int k0) {
        char* base = sm + bufi * 16384;
#pragma unroll
        for (int j = 0; j < 2; ++j) {
            int rb = w * 16 + j * 8;
            int row = rb + r8;
            size_t aoff = ((size_t)(o0 + row) * INNER + k0) * 2 + kswz;
            size_t boff = (((size_t)b * PP + p0 + row) * INNER + k0) * 2 + kswz;
            gload16((const char*)WHp + aoff, base + rb * 128);
            gload16((const char*)Xt + boff, base + 8192 + rb * 128);
        }
    };

    STAGE(0, 0);
    __syncthreads();
    int cur = 0;
    for (int t = 0; t < 8; ++t) {
        if (t < 7) STAGE(cur ^ 1, (t + 1) * 64);
        char* AH = sm + cur * 16384;
        char* BH = AH + 8192;
#pragma unroll
        for (int kk = 0; kk < 2; ++kk) {
            int kb = kk * 64 + lk * 16;
            short8 ah[2], bh[2];
#pragma unroll
            for (int f = 0; f < 2; ++f) {
                ah[f] = *(short8*)(AH + sw(wm * 32 + f * 16 + lr, kb));
                bh[f] = *(short8*)(BH + sw(wn * 32 + f * 16 + lr, kb));
            }
#pragma unroll
            for (int fm = 0; fm < 2; ++fm)
#pragma unroll
                for (int fn = 0; fn < 2; ++fn)
                    acc[fm][fn] = __builtin_amdgcn_mfma_f32_16x16x32_bf16(ah[fm], bh[fn], acc[fm][fn], 0, 0, 0);
        }
        __syncthreads();
        cur ^= 1;
    }
#pragma unroll
    for (int fm = 0; fm < 2; ++fm)
#pragma unroll
        for (int fn = 0; fn < 2; ++fn)
#pragma unroll
            for (int r = 0; r < 4; ++r)
                Y[((size_t)b * CDIM + o0 + wm * 32 + fm * 16 + lk * 4 + r) * PP
                  + p0 + wn * 32 + fn * 16 + lr] = f2h(acc[fm][fn][r]);
}

// ---------------- K7: final LN (y bf16) + gamma*out + residual ----------------
__global__ __launch_bounds__(256) void final_ln_kernel(const u16* __restrict__ y,
                                                       const float* __restrict__ g,
                                                       const float* __restrict__ bb,
                                                       const float* __restrict__ gamma,
                                                       const float* __restrict__ resid,
                                                       float* __restrict__ out) {
    int b = blockIdx.y;
    int p = blockIdx.x * 256 + threadIdx.x;
    const u16* yb = y + (size_t)b * CDIM * PP + p;
    float s = 0.f, sq = 0.f;
    for (int c = 0; c < CDIM; ++c) {
        float v = h2f(yb[(size_t)c * PP]);
        s += v; sq += v * v;
    }
    float mean = s * (1.f / CDIM);
    float var  = sq * (1.f / CDIM) - mean * mean;
    float rstd = rsqrtf(var + 1e-5f);
    float gm = gamma[0];
    const float* rb = resid + (size_t)b * CDIM * PP + p;
    float* ob = out + (size_t)b * CDIM * PP + p;
    for (int c = 0; c < CDIM; ++c) {
        float v = h2f(yb[(size_t)c * PP]);
        float xn = (v - mean) * rstd * g[c] + bb[c];
        ob[(size_t)c * PP] = gm * xn + rb[(size_t)c * PP];
    }
}

extern "C" void kernel_launch(void* const* d_in, const int* in_sizes, int n_in,
                              void* d_out, int out_size, void* d_ws, size_t ws_size,
                              hipStream_t stream) {
    const float* query_source = (const float*)d_in[0];
    const float* context      = (const float*)d_in[1];
    const float* cn_g = (const float*)d_in[2];
    const float* cn_b = (const float*)d_in[3];
    const float* qn_g = (const float*)d_in[4];
    const float* qn_b = (const float*)d_in[5];
    const float* on_g = (const float*)d_in[6];
    const float* on_b = (const float*)d_in[7];
    const float* w_kv = (const float*)d_in[8];
    const float* w_q  = (const float*)d_in[9];
    const float* w_out= (const float*)d_in[10];
    const float* gamma= (const float*)d_in[11];
    float* out = (float*)d_out;

    char* ws = (char*)d_ws;
    u16*  XHt    = (u16*)(ws + 0);             // 16M
    u16*  XLt    = (u16*)(ws + 16777216);      // 16M
    u16*  attn_t = (u16*)(ws + 0);             // 32M (X staging dead)
    u16*  k_n  = (u16*)(ws + 33554432);        // 16M
    u16*  y    = (u16*)(ws + 33554432);        // 16M bf16 (k_n dead after gather)
    u16*  v_s  = (u16*)(ws + 67108864);        // 16M
    u16*  q_t  = (u16*)(ws + 100663296);       // 32M transposed q [bh][p][d]
    u16*  WqH   = (u16*)(ws + 134217728);      // 512K (dead after q GEMM)
    u16*  WqL   = (u16*)(ws + 134742016);      // 512K
    u16*  k_sel = (u16*)(ws + 134217728);      // aliases WqH
    u16*  v_selt= (u16*)(ws + 134742016);      // aliases WqL
    u16*  WkvH  = (u16*)(ws + 135266304);      // 512K
    u16*  WkvL  = (u16*)(ws + 135790592);      // 512K
    u16*  WoutH = (u16*)(ws + 135266304);      // 256K, aliases WkvH (dead after kv GEMM)
    float* qprobe_part   = (float*)(ws + 136314880); // 1M
    float* colscore_part = (float*)(ws + 136314880); // 1M alias
    float* q_probe       = (float*)(ws + 137363456); // 16K

    dim3 blk(256);
    split2_kernel<<<dim3(1536), blk, 0, stream>>>(w_kv, w_q, WkvH, WkvL, WqH, WqL);
    // ---- q pipeline ----
    ln_split_kernel<<<dim3(64, BB), blk, 0, stream>>>(query_source, qn_g, qn_b, XHt, XLt);
    mfma_fused_kernel<<<dim3(4, 64, BB), blk, 0, stream>>>(WqH, WqL, XHt, XLt, q_t, nullptr,
                                                           1, qprobe_part, nullptr);
    qreduce_kernel<<<dim3(64), dim3(64), 0, stream>>>(qprobe_part, q_probe);
    // ---- kv pipeline ----
    ln_split_kernel<<<dim3(64, BB), blk, 0, stream>>>(context, cn_g, cn_b, XHt, XLt);
    mfma_fused_kernel<<<dim3(8, 64, BB), blk, 0, stream>>>(WkvH, WkvL, XHt, XLt, k_n, v_s,
                                                           0, colscore_part, q_probe);
    // ---- select / attention / output ----
    select_gather_kernel<<<dim3(64), blk, 0, stream>>>(colscore_part, k_n, v_s, k_sel, v_selt);
    wsplit_hi_kernel<<<dim3(512), blk, 0, stream>>>(w_out, WoutH);
    attn_mfma_kernel<<<dim3(64, NBH), blk, 0, stream>>>(q_t, k_sel, v_selt, attn_t);
    mfma_out_kernel<<<dim3(4, 64, BB), blk, 0, stream>>>(WoutH, attn_t, y);
    final_ln_kernel<<<dim3(16, BB), blk, 0, stream>>>(y, on_g, on_b, gamma, query_source, out);
}